// Round 4
// baseline (25513.519 us; speedup 1.0000x reference)
//
#include <hip/hip_runtime.h>
#include <hip/hip_bf16.h>
#include <hip/hip_cooperative_groups.h>
#include <cmath>

#define NN 2048
#define TT 256
#define DD 16
#define HH 256

typedef __attribute__((ext_vector_type(8))) short short8;
typedef __attribute__((ext_vector_type(4))) float f32x4;

__device__ __forceinline__ float sigmoidf_(float x){ return 1.0f/(1.0f+expf(-x)); }

// async 16B/lane global->LDS (LDS dest wave-uniform base; HW adds lane*16)
__device__ __forceinline__ void glds16(const __hip_bfloat16* g, __hip_bfloat16* l){
  __builtin_amdgcn_global_load_lds(
      (const __attribute__((address_space(1))) void*)g,
      (__attribute__((address_space(3))) void*)l, 16, 0, 0);
}

// ---------------- packing ----------------
// W (1024x256) -> P [jg 16][p 2][64 rows g*16+jj][256 k] bf16 hi/lo
__global__ __launch_bounds__(256) void pack_ws(const float* __restrict__ W,
                                               __hip_bfloat16* __restrict__ P){
  int tid = blockIdx.x*256 + threadIdx.x;     // 1024 blocks
  int row = tid >> 8, k = tid & 255;
  int g = row >> 8, rem = row & 255, jgi = rem >> 4, jj = rem & 15;
  float w = W[(size_t)row*256 + k];
  __hip_bfloat16 h = __float2bfloat16(w);
  __hip_bfloat16 l = __float2bfloat16(w - __bfloat162float(h));
  size_t b = ((size_t)(jgi*2)*64 + (g<<4) + jj)*256 + k;
  P[b] = h; P[b + 16384] = l;
}
// Wih0 (1024x16) -> [jg][64 rows][64]: [hi|hi|lo|0] (pairs with x [hi|lo|hi|0])
__global__ __launch_bounds__(256) void pack_w0s(const float* __restrict__ W,
                                                __hip_bfloat16* __restrict__ P){
  int tid = blockIdx.x*256 + threadIdx.x;     // 64 blocks
  int row = tid >> 4, k = tid & 15;
  int g = row >> 8, rem = row & 255, jgi = rem >> 4, jj = rem & 15;
  float w = W[tid];
  __hip_bfloat16 h = __float2bfloat16(w);
  __hip_bfloat16 l = __float2bfloat16(w - __bfloat162float(h));
  size_t b = ((size_t)jgi*64 + (g<<4) + jj)*64;
  P[b + k] = h; P[b + 16 + k] = h; P[b + 32 + k] = l;
  P[b + 48 + k] = __float2bfloat16(0.0f);
}
// x (N,T,16) -> Xp (N,T,64): [hi | lo | hi | 0]
__global__ __launch_bounds__(256) void pack_x(const float* __restrict__ x,
                                              __hip_bfloat16* __restrict__ Xp){
  int tid = blockIdx.x*256 + threadIdx.x;     // 2048 blocks
  const float* xr = x + (size_t)tid*16;
  __hip_bfloat16* o = Xp + (size_t)tid*64;
  for (int k=0;k<16;k++){
    float v = xr[k];
    __hip_bfloat16 h = __float2bfloat16(v);
    __hip_bfloat16 l = __float2bfloat16(v - __bfloat162float(h));
    o[k] = h; o[16+k] = l; o[32+k] = h; o[48+k] = __float2bfloat16(0.0f);
  }
}
__global__ __launch_bounds__(256) void recon_nf(const __hip_bfloat16* __restrict__ hi,
    const __hip_bfloat16* __restrict__ lo, float* __restrict__ nf){
  int tid = blockIdx.x*256 + threadIdx.x;
  nf[tid] = __bfloat162float(hi[tid]) + __bfloat162float(lo[tid]);
}

// ---------------- persistent fused two-layer LSTM ----------------
// 256 blocks x 512 thr (1/CU). Block owns (m-range 128, j-range 16), both layers.
// waves 0-3: L0 epoch t; waves 4-7: L1 epoch t-1 (skewed). 257 grid syncs.
// Whh-hi in regs (k-half split), Wih1-hi in LDS, lo-weights + h tiles streamed.
__global__ __launch_bounds__(512, 2) void lstm_persist(
    const __hip_bfloat16* __restrict__ Xp,
    const __hip_bfloat16* __restrict__ P0ih,
    const __hip_bfloat16* __restrict__ P0hh,
    const __hip_bfloat16* __restrict__ P1ih,
    const __hip_bfloat16* __restrict__ P1hh,
    const float* __restrict__ bih0, const float* __restrict__ bhh0,
    const float* __restrict__ bih1, const float* __restrict__ bhh1,
    __hip_bfloat16* h0hiA, __hip_bfloat16* h0loA,
    __hip_bfloat16* h0hiB, __hip_bfloat16* h0loB,
    __hip_bfloat16* h1hiA, __hip_bfloat16* h1loA,
    __hip_bfloat16* h1hiB, __hip_bfloat16* h1loB)
{
  cooperative_groups::grid_group grid = cooperative_groups::this_grid();

  __shared__ __align__(16) __hip_bfloat16 WihL[64*264];      // Wih1-hi, pad 264
  __shared__ __align__(16) __hip_bfloat16 Ast[2][2][128*64]; // [quad][buf] A stage
  __shared__ __align__(16) __hip_bfloat16 Bst[2][2][64*64];  // [quad][buf] lo-W stage

  const int bid = blockIdx.x;
  const int mg = ((bid&7)<<1) + (bid>>7);   // XCD-swizzled m-group
  const int jg = (bid>>3)&15;
  const int m0 = mg<<7, j0 = jg<<4;
  const int tid = threadIdx.x, wv = tid>>6, lane = tid&63;
  const bool isL0 = wv < 4;
  const int quad = isL0 ? 0 : 1;
  const int qw = wv & 3;
  const int mh = qw >> 1;                   // m-half of 128
  const int kh = qw & 1;                    // k-half of each k64 chunk
  const int rr = lane>>3;
  const int sw8 = (((lane&7)^rr)<<3);       // source-side XOR swizzle
  const int kc = (kh<<2) + (lane>>4);
  const int sl8 = ((kc ^ (lane&7))<<3);     // LDS read slot
  const int frow = lane&15;
  const int fk8 = (lane>>4)<<3;

  __hip_bfloat16* h0hi[2] = {h0hiA, h0hiB};
  __hip_bfloat16* h0lo[2] = {h0loA, h0loB};
  __hip_bfloat16* h1hi[2] = {h1hiA, h1hiB};
  __hip_bfloat16* h1lo[2] = {h1loA, h1loB};

  // ---- init: Wih1-hi -> LDS (padded rows) ----
  {
    const __hip_bfloat16* src = P1ih + (size_t)(jg*2)*16384;
    for (int i = tid; i < 64*32; i += 512){
      int r = i>>5, c8 = (i&31)<<3;
      *reinterpret_cast<short8*>(&WihL[r*264 + c8]) =
        *reinterpret_cast<const short8*>(&src[(size_t)r*256 + c8]);
    }
  }
  // ---- init: Whh-hi fragments -> regs (own k-half only) ----
  short8 Wf[16];
  {
    const __hip_bfloat16* Pm = isL0 ? P0hh : P1hh;
    const __hip_bfloat16* b = Pm + (size_t)(jg*2)*16384;
    #pragma unroll
    for (int c=0;c<4;c++)
      #pragma unroll
      for (int g=0;g<4;g++)
        Wf[c*4+g] = *reinterpret_cast<const short8*>(
           &b[(size_t)((g<<4)+frow)*256 + c*64 + kh*32 + fk8]);
  }
  short8 W0f[4];
  if (isL0){
    #pragma unroll
    for (int g=0;g<4;g++)
      W0f[g] = *reinterpret_cast<const short8*>(
        &P0ih[(size_t)(jg*64 + (g<<4) + frow)*64 + kh*32 + fk8]);
  }
  float bsum[4];
  {
    const float* bi = isL0 ? bih0 : bih1;
    const float* bh = isL0 ? bhh0 : bhh1;
    #pragma unroll
    for (int g=0;g<4;g++) bsum[g] = bi[(g<<8) + j0 + frow] + bh[(g<<8) + j0 + frow];
  }
  float cst[16];
  #pragma unroll
  for (int i=0;i<16;i++) cst[i] = 0.f;

  __syncthreads();

  for (int t=0; t<=TT; ++t){
    const int pb = (t+1)&1;   // prev h buffer
    const int ob = t&1;       // out h buffer

    // slot descriptor. mode: 0=Wf regs, 1=WihL LDS, 2=W0f regs
    auto desc = [&](int s, const __hip_bfloat16*& Asrc, size_t& lda, int& kb,
                    int& mode, const __hip_bfloat16*& BloSrc)->bool {
      Asrc=nullptr; BloSrc=nullptr; lda=256; kb=(s&3)<<6; mode=0;
      if (isL0){
        if (t>=TT) return false;
        if (s<8){
          if (t==0) return false;
          Asrc = (s<4 ? h0hi[pb] : h0lo[pb]);
          if (s<4) BloSrc = P0hh + (size_t)(jg*2+1)*16384;
          return true;
        } else if (s==8){
          Asrc = Xp + (size_t)t*64; lda = (size_t)TT*64; kb = 0; mode = 2;
          return true;
        }
        return false;
      } else {
        if (t<1) return false;
        if (s<8){
          Asrc = (s<4 ? h0hi[pb] : h0lo[pb]); mode = 1;
          if (s<4) BloSrc = P1ih + (size_t)(jg*2+1)*16384;
          return true;
        } else {
          if (t<2) return false;
          Asrc = (s<12 ? h1hi[pb] : h1lo[pb]); mode = 0;
          if (s<12) BloSrc = P1hh + (size_t)(jg*2+1)*16384;
          return true;
        }
      }
    };
    auto stage = [&](int s, int nb){
      const __hip_bfloat16* Asrc; size_t lda; int kb; int mode; const __hip_bfloat16* BloSrc;
      if (!desc(s, Asrc, lda, kb, mode, BloSrc)) return;
      const __hip_bfloat16* Ab = Asrc + (size_t)(m0 + qw*32 + rr)*lda + kb + sw8;
      __hip_bfloat16* Ad = &Ast[quad][nb][(qw*32)*64];
      #pragma unroll
      for (int c2=0;c2<4;c2++)
        glds16(Ab + (size_t)(c2*8)*lda, Ad + c2*8*64);
      if (BloSrc){
        const __hip_bfloat16* Bb = BloSrc + (size_t)((qw<<4) + rr)*256 + kb + sw8;
        __hip_bfloat16* Bd = &Bst[quad][nb][(qw<<4)*64];
        #pragma unroll
        for (int c2=0;c2<2;c2++)
          glds16(Bb + (size_t)(c2*8)*256, Bd + c2*8*64);
      }
    };

    f32x4 acc[4][4] = {};   // [m-tile][gate]

    stage(0, 0);
    __syncthreads();
    for (int s=0; s<16; ++s){
      if (s<15) stage(s+1, (s+1)&1);
      {
        const __hip_bfloat16* Asrc; size_t lda; int kb; int mode; const __hip_bfloat16* BloSrc;
        if (desc(s, Asrc, lda, kb, mode, BloSrc)){
          const int nb = s&1;
          const int c = s&3;
          short8 a[4];
          const __hip_bfloat16* Ab = Ast[quad][nb];
          #pragma unroll
          for (int mt=0;mt<4;mt++)
            a[mt] = *reinterpret_cast<const short8*>(
              &Ab[(size_t)((mh<<6) + (mt<<4) + frow)*64 + sl8]);
          if (mode==0){
            #pragma unroll
            for (int g=0;g<4;g++){
              short8 b = Wf[c*4+g];
              #pragma unroll
              for (int mt=0;mt<4;mt++)
                acc[mt][g] = __builtin_amdgcn_mfma_f32_16x16x32_bf16(a[mt], b, acc[mt][g], 0,0,0);
            }
          } else if (mode==1){
            #pragma unroll
            for (int g=0;g<4;g++){
              short8 b = *reinterpret_cast<const short8*>(
                 &WihL[(size_t)((g<<4)+frow)*264 + kb + kh*32 + fk8]);
              #pragma unroll
              for (int mt=0;mt<4;mt++)
                acc[mt][g] = __builtin_amdgcn_mfma_f32_16x16x32_bf16(a[mt], b, acc[mt][g], 0,0,0);
            }
          } else {
            #pragma unroll
            for (int g=0;g<4;g++){
              short8 b = W0f[g];
              #pragma unroll
              for (int mt=0;mt<4;mt++)
                acc[mt][g] = __builtin_amdgcn_mfma_f32_16x16x32_bf16(a[mt], b, acc[mt][g], 0,0,0);
            }
          }
          if (BloSrc){
            #pragma unroll
            for (int g=0;g<4;g++){
              short8 bl = *reinterpret_cast<const short8*>(
                 &Bst[quad][nb][(size_t)((g<<4)+frow)*64 + sl8]);
              #pragma unroll
              for (int mt=0;mt<4;mt++)
                acc[mt][g] = __builtin_amdgcn_mfma_f32_16x16x32_bf16(a[mt], bl, acc[mt][g], 0,0,0);
            }
          }
        }
      }
      __syncthreads();
    }

    // ---- k-half reduce (reuse Ast[quad] as 32KB f32 buffer) + epilogue ----
    const bool qact = isL0 ? (t<TT) : (t>=1);
    float* rb = reinterpret_cast<float*>(&Ast[quad][0][0]);
    if (qact && kh==1){
      #pragma unroll
      for (int mt=0;mt<4;mt++)
        #pragma unroll
        for (int g=0;g<4;g++)
          #pragma unroll
          for (int r=0;r<4;r++)
            rb[(size_t)((mt<<4)+(g<<2)+r)*128 + (mh<<6) + lane] = acc[mt][g][r];
    }
    __syncthreads();
    if (qact && kh==0){
      #pragma unroll
      for (int mt=0;mt<4;mt++)
        #pragma unroll
        for (int g=0;g<4;g++)
          #pragma unroll
          for (int r=0;r<4;r++)
            acc[mt][g][r] += rb[(size_t)((mt<<4)+(g<<2)+r)*128 + (mh<<6) + lane];
      __hip_bfloat16* ohi = isL0 ? h0hi[ob] : h1hi[ob];
      __hip_bfloat16* olo = isL0 ? h0lo[ob] : h1lo[ob];
      #pragma unroll
      for (int mt=0;mt<4;mt++){
        #pragma unroll
        for (int r=0;r<4;r++){
          float gi = acc[mt][0][r] + bsum[0];
          float gf = acc[mt][1][r] + bsum[1];
          float gg = acc[mt][2][r] + bsum[2];
          float go = acc[mt][3][r] + bsum[3];
          float cold = cst[(mt<<2)+r];
          float cn = sigmoidf_(gf)*cold + sigmoidf_(gi)*tanhf(gg);
          float hv = sigmoidf_(go)*tanhf(cn);
          cst[(mt<<2)+r] = cn;
          int m = m0 + (mh<<6) + (mt<<4) + ((lane>>4)<<2) + r;
          size_t mi = (size_t)m*HH + j0 + frow;
          __hip_bfloat16 hb = __float2bfloat16(hv);
          ohi[mi] = hb;
          olo[mi] = __float2bfloat16(hv - __bfloat162float(hb));
        }
      }
    }
    __syncthreads();
    __threadfence();
    grid.sync();
  }
}

// ---------------- fp32 tail (unchanged, proven) ----------------
__global__ __launch_bounds__(256) void gemm_nn(
    float* __restrict__ C, const float* __restrict__ A, const float* __restrict__ B,
    int K, int lda, int ldb, int ldc, int relu)
{
  __shared__ float As_[16][68];
  __shared__ float Bs_[16][64];
  float acc[4][4] = {};
  const int tx = threadIdx.x;
  const int m0 = blockIdx.y<<6, n0 = blockIdx.x<<6;
  const int am = tx>>2, ak = (tx&3)<<2;
  const int bk = tx>>4, bn = (tx&15)<<2;
  const int mm = (tx>>4)<<2, nc = (tx&15)<<2;
  for (int kb=0; kb<K; kb+=16){
    float4 av = *reinterpret_cast<const float4*>(A + (size_t)(m0+am)*lda + kb + ak);
    As_[ak][am]=av.x; As_[ak+1][am]=av.y; As_[ak+2][am]=av.z; As_[ak+3][am]=av.w;
    *reinterpret_cast<float4*>(&Bs_[bk][bn]) =
      *reinterpret_cast<const float4*>(B + (size_t)(kb+bk)*ldb + n0 + bn);
    __syncthreads();
    #pragma unroll
    for (int k=0;k<16;k++){
      float4 a4 = *reinterpret_cast<const float4*>(&As_[k][mm]);
      float4 b4 = *reinterpret_cast<const float4*>(&Bs_[k][nc]);
      acc[0][0]=fmaf(a4.x,b4.x,acc[0][0]); acc[0][1]=fmaf(a4.x,b4.y,acc[0][1]);
      acc[0][2]=fmaf(a4.x,b4.z,acc[0][2]); acc[0][3]=fmaf(a4.x,b4.w,acc[0][3]);
      acc[1][0]=fmaf(a4.y,b4.x,acc[1][0]); acc[1][1]=fmaf(a4.y,b4.y,acc[1][1]);
      acc[1][2]=fmaf(a4.y,b4.z,acc[1][2]); acc[1][3]=fmaf(a4.y,b4.w,acc[1][3]);
      acc[2][0]=fmaf(a4.z,b4.x,acc[2][0]); acc[2][1]=fmaf(a4.z,b4.y,acc[2][1]);
      acc[2][2]=fmaf(a4.z,b4.z,acc[2][2]); acc[2][3]=fmaf(a4.z,b4.w,acc[2][3]);
      acc[3][0]=fmaf(a4.w,b4.x,acc[3][0]); acc[3][1]=fmaf(a4.w,b4.y,acc[3][1]);
      acc[3][2]=fmaf(a4.w,b4.z,acc[3][2]); acc[3][3]=fmaf(a4.w,b4.w,acc[3][3]);
    }
    __syncthreads();
  }
  #pragma unroll
  for (int r=0;r<4;r++){
    float4 v = make_float4(acc[r][0],acc[r][1],acc[r][2],acc[r][3]);
    if (relu){ v.x=fmaxf(v.x,0.f); v.y=fmaxf(v.y,0.f); v.z=fmaxf(v.z,0.f); v.w=fmaxf(v.w,0.f); }
    *reinterpret_cast<float4*>(C + (size_t)(m0+mm+r)*ldc + n0 + nc) = v;
  }
}

__global__ __launch_bounds__(256) void gemm_nt(
    float* __restrict__ C, const float* __restrict__ A, const float* __restrict__ B,
    int K, int lda, int ldb, int ldc)
{
  __shared__ float As_[16][68];
  __shared__ float Bs_[16][68];
  float acc[4][4] = {};
  const int tx = threadIdx.x;
  const int m0 = blockIdx.y<<6, n0 = blockIdx.x<<6;
  const int am = tx>>2, ak = (tx&3)<<2;
  const int mm = (tx>>4)<<2, nc = (tx&15)<<2;
  for (int kb=0; kb<K; kb+=16){
    float4 av = *reinterpret_cast<const float4*>(A + (size_t)(m0+am)*lda + kb + ak);
    As_[ak][am]=av.x; As_[ak+1][am]=av.y; As_[ak+2][am]=av.z; As_[ak+3][am]=av.w;
    float4 bv = *reinterpret_cast<const float4*>(B + (size_t)(n0+am)*ldb + kb + ak);
    Bs_[ak][am]=bv.x; Bs_[ak+1][am]=bv.y; Bs_[ak+2][am]=bv.z; Bs_[ak+3][am]=bv.w;
    __syncthreads();
    #pragma unroll
    for (int k=0;k<16;k++){
      float4 a4 = *reinterpret_cast<const float4*>(&As_[k][mm]);
      float4 b4 = *reinterpret_cast<const float4*>(&Bs_[k][nc]);
      acc[0][0]=fmaf(a4.x,b4.x,acc[0][0]); acc[0][1]=fmaf(a4.x,b4.y,acc[0][1]);
      acc[0][2]=fmaf(a4.x,b4.z,acc[0][2]); acc[0][3]=fmaf(a4.x,b4.w,acc[0][3]);
      acc[1][0]=fmaf(a4.y,b4.x,acc[1][0]); acc[1][1]=fmaf(a4.y,b4.y,acc[1][1]);
      acc[1][2]=fmaf(a4.y,b4.z,acc[1][2]); acc[1][3]=fmaf(a4.y,b4.w,acc[1][3]);
      acc[2][0]=fmaf(a4.z,b4.x,acc[2][0]); acc[2][1]=fmaf(a4.z,b4.y,acc[2][1]);
      acc[2][2]=fmaf(a4.z,b4.z,acc[2][2]); acc[2][3]=fmaf(a4.z,b4.w,acc[2][3]);
      acc[3][0]=fmaf(a4.w,b4.x,acc[3][0]); acc[3][1]=fmaf(a4.w,b4.y,acc[3][1]);
      acc[3][2]=fmaf(a4.w,b4.z,acc[3][2]); acc[3][3]=fmaf(a4.w,b4.w,acc[3][3]);
    }
    __syncthreads();
  }
  #pragma unroll
  for (int r=0;r<4;r++){
    float4 v = make_float4(acc[r][0],acc[r][1],acc[r][2],acc[r][3]);
    *reinterpret_cast<float4*>(C + (size_t)(m0+mm+r)*ldc + n0 + nc) = v;
  }
}

__global__ __launch_bounds__(256) void rowstat(const float* __restrict__ nf,
    float* __restrict__ xc, float* __restrict__ dvec)
{
  __shared__ float red[256];
  int n = blockIdx.x, tx = threadIdx.x;
  float v = nf[(size_t)n*HH + tx];
  red[tx] = v; __syncthreads();
  for (int s=128; s>0; s>>=1){ if (tx<s) red[tx]+=red[tx+s]; __syncthreads(); }
  float mean = red[0] * (1.0f/HH);
  __syncthreads();
  float d = v - mean;
  xc[(size_t)n*HH + tx] = d;
  red[tx] = d*d; __syncthreads();
  for (int s=128; s>0; s>>=1){ if (tx<s) red[tx]+=red[tx+s]; __syncthreads(); }
  if (tx==0) dvec[n] = sqrtf(red[0]);
}

__global__ __launch_bounds__(256) void rowsum(const float* __restrict__ cov,
    const float* __restrict__ dvec, float* __restrict__ dinv)
{
  __shared__ float red[256];
  int i = blockIdx.x, tx = threadIdx.x;
  float di = dvec[i];
  float s = 0.f;
  for (int jj=tx; jj<NN; jj+=256){
    float r = cov[(size_t)i*NN + jj] / (di * dvec[jj]);
    if (r != r) r = 0.f; else r = fminf(1.f, fmaxf(-1.f, r));
    s += r;
  }
  red[tx]=s; __syncthreads();
  for (int st=128; st>0; st>>=1){ if (tx<st) red[tx]+=red[tx+st]; __syncthreads(); }
  if (tx==0){
    float tot = red[0] + 1.0f;
    float p = powf(tot, -0.5f);
    if (isinf(p)) p = 0.f;
    dinv[i] = p;
  }
}

__global__ __launch_bounds__(256) void adjnorm(float* __restrict__ cov,
    const float* __restrict__ dvec, const float* __restrict__ dinv)
{
  size_t idx = (size_t)blockIdx.x*256 + threadIdx.x;
  int i = (int)(idx >> 11), jj = (int)(idx & (NN-1));
  float r = cov[idx] / (dvec[i]*dvec[jj]);
  if (r != r) r = 0.f; else r = fminf(1.f, fmaxf(-1.f, r));
  if (i==jj) r += 1.f;
  cov[idx] = dinv[i]*r*dinv[jj];
}

__global__ __launch_bounds__(128) void predk(const float* __restrict__ G2,
    const float* __restrict__ Wfc, const float* __restrict__ bfc, float* __restrict__ out)
{
  int n = blockIdx.x, tx = threadIdx.x;
  float v = G2[(size_t)n*128 + tx] * Wfc[tx];
  for (int off=32; off>0; off>>=1) v += __shfl_down(v, off);
  __shared__ float p[2];
  if ((tx&63)==0) p[tx>>6] = v;
  __syncthreads();
  if (tx==0) out[n] = p[0] + p[1] + bfc[0];
}

extern "C" void kernel_launch(void* const* d_in, const int* in_sizes, int n_in,
                              void* d_out, int out_size, void* d_ws, size_t ws_size,
                              hipStream_t stream)
{
  const float* x    = (const float*)d_in[0];
  const float* Wih0 = (const float*)d_in[1];
  const float* Whh0 = (const float*)d_in[2];
  const float* bih0 = (const float*)d_in[3];
  const float* bhh0 = (const float*)d_in[4];
  const float* Wih1 = (const float*)d_in[5];
  const float* Whh1 = (const float*)d_in[6];
  const float* bih1 = (const float*)d_in[7];
  const float* bhh1 = (const float*)d_in[8];
  const float* Wg1  = (const float*)d_in[9];
  const float* Wg2  = (const float*)d_in[10];
  const float* Wfc  = (const float*)d_in[11];
  const float* bfc  = (const float*)d_in[12];
  float* out = (float*)d_out;

  char* w = (char*)d_ws;
  auto alloc = [&](size_t bytes){ char* p = w; w += (bytes + 255) & ~(size_t)255; return p; };
  __hip_bfloat16* Xp   = (__hip_bfloat16*)alloc((size_t)NN*TT*64*2);
  __hip_bfloat16* P0hh = (__hip_bfloat16*)alloc((size_t)1024*512*2);
  __hip_bfloat16* P1ih = (__hip_bfloat16*)alloc((size_t)1024*512*2);
  __hip_bfloat16* P1hh = (__hip_bfloat16*)alloc((size_t)1024*512*2);
  __hip_bfloat16* P0ih = (__hip_bfloat16*)alloc((size_t)1024*64*2);
  __hip_bfloat16 *H0hi[2], *H0lo[2], *H1hi[2], *H1lo[2];
  for (int i=0;i<2;i++){ H0hi[i]=(__hip_bfloat16*)alloc((size_t)NN*HH*2);
                         H0lo[i]=(__hip_bfloat16*)alloc((size_t)NN*HH*2); }
  for (int i=0;i<2;i++){ H1hi[i]=(__hip_bfloat16*)alloc((size_t)NN*HH*2);
                         H1lo[i]=(__hip_bfloat16*)alloc((size_t)NN*HH*2); }
  float* nf   = (float*)alloc((size_t)NN*HH*4);
  float* xc   = (float*)alloc((size_t)NN*HH*4);
  float* cov  = (float*)alloc((size_t)NN*NN*4);
  float* t1   = (float*)alloc((size_t)NN*HH*4);
  float* G1   = (float*)alloc((size_t)NN*HH*4);
  float* t2   = (float*)alloc((size_t)NN*128*4);
  float* G2   = (float*)alloc((size_t)NN*128*4);
  float* dvec = (float*)alloc((size_t)NN*4);
  float* dinv = (float*)alloc((size_t)NN*4);

  hipLaunchKernelGGL(pack_ws,  dim3(1024), dim3(256), 0, stream, Whh0, P0hh);
  hipLaunchKernelGGL(pack_ws,  dim3(1024), dim3(256), 0, stream, Wih1, P1ih);
  hipLaunchKernelGGL(pack_ws,  dim3(1024), dim3(256), 0, stream, Whh1, P1hh);
  hipLaunchKernelGGL(pack_w0s, dim3(64),   dim3(256), 0, stream, Wih0, P0ih);
  hipLaunchKernelGGL(pack_x,   dim3(2048), dim3(256), 0, stream, x, Xp);

  {
    const __hip_bfloat16 *aXp = Xp, *aP0ih = P0ih, *aP0hh = P0hh, *aP1ih = P1ih, *aP1hh = P1hh;
    __hip_bfloat16 *a0hA = H0hi[0], *a0lA = H0lo[0], *a0hB = H0hi[1], *a0lB = H0lo[1];
    __hip_bfloat16 *a1hA = H1hi[0], *a1lA = H1lo[0], *a1hB = H1hi[1], *a1lB = H1lo[1];
    const float *ab0 = bih0, *ab1 = bhh0, *ab2 = bih1, *ab3 = bhh1;
    void* args[] = {
      (void*)&aXp, (void*)&aP0ih, (void*)&aP0hh, (void*)&aP1ih, (void*)&aP1hh,
      (void*)&ab0, (void*)&ab1, (void*)&ab2, (void*)&ab3,
      (void*)&a0hA, (void*)&a0lA, (void*)&a0hB, (void*)&a0lB,
      (void*)&a1hA, (void*)&a1lA, (void*)&a1hB, (void*)&a1lB };
    hipLaunchCooperativeKernel((const void*)lstm_persist, dim3(256), dim3(512),
                               args, 0, stream);
  }
  // t=256 (even) wrote h1 into buffer 0
  hipLaunchKernelGGL(recon_nf, dim3(2048), dim3(256), 0, stream, H1hi[0], H1lo[0], nf);

  hipLaunchKernelGGL(rowstat, dim3(NN), dim3(256), 0, stream, nf, xc, dvec);
  hipLaunchKernelGGL(gemm_nt, dim3(NN/64, NN/64), dim3(256), 0, stream,
      cov, xc, xc, HH, HH, HH, NN);
  hipLaunchKernelGGL(rowsum, dim3(NN), dim3(256), 0, stream, cov, dvec, dinv);
  hipLaunchKernelGGL(adjnorm, dim3(NN*NN/256), dim3(256), 0, stream, cov, dvec, dinv);

  hipLaunchKernelGGL(gemm_nn, dim3(HH/64, NN/64), dim3(256), 0, stream,
      t1, nf, Wg1, HH, HH, HH, HH, 0);
  hipLaunchKernelGGL(gemm_nn, dim3(HH/64, NN/64), dim3(256), 0, stream,
      G1, cov, t1, NN, NN, HH, HH, 1);
  hipLaunchKernelGGL(gemm_nn, dim3(128/64, NN/64), dim3(256), 0, stream,
      t2, G1, Wg2, HH, HH, 128, 128, 0);
  hipLaunchKernelGGL(gemm_nn, dim3(128/64, NN/64), dim3(256), 0, stream,
      G2, cov, t2, NN, NN, 128, 128, 0);
  hipLaunchKernelGGL(predk, dim3(NN), dim3(128), 0, stream, G2, Wfc, bfc, out);
}

// Round 7
// 10778.984 us; speedup vs baseline: 2.3670x; 2.3670x over previous
//
#include <hip/hip_runtime.h>
#include <hip/hip_bf16.h>
#include <cmath>

#define NN 2048
#define TT 256
#define DD 16
#define HH 256

typedef __attribute__((ext_vector_type(8))) short short8;
typedef __attribute__((ext_vector_type(4))) float f32x4;

__device__ __forceinline__ float sigmoidf_(float x){ return 1.0f/(1.0f+expf(-x)); }

// async 16B/lane global->LDS (LDS dest wave-uniform base; HW adds lane*16)
__device__ __forceinline__ void glds16(const __hip_bfloat16* g, __hip_bfloat16* l){
  __builtin_amdgcn_global_load_lds(
      (const __attribute__((address_space(1))) void*)g,
      (__attribute__((address_space(3))) void*)l, 16, 0, 0);
}

// ---------------- packing ----------------
// W (1024x256) -> P (1024x512): [hi | lo]
__global__ __launch_bounds__(256) void pack_w2(const float* __restrict__ W,
                                               __hip_bfloat16* __restrict__ P){
  int tid = blockIdx.x*256 + threadIdx.x;   // 1024 blocks
  int r = tid >> 8, k = tid & 255;
  float w = W[tid];
  __hip_bfloat16 h = __float2bfloat16(w);
  __hip_bfloat16 l = __float2bfloat16(w - __bfloat162float(h));
  size_t base = (size_t)r*512;
  P[base + k] = h; P[base + 256 + k] = l;
}
// Wih0 (1024 x 16) -> (1024 x 64): [hi | hi | lo | 0] (pairs with x [hi|lo|hi|0])
__global__ __launch_bounds__(256) void pack_w0(const float* __restrict__ W,
                                               __hip_bfloat16* __restrict__ P){
  int tid = blockIdx.x*256 + threadIdx.x;   // 64 blocks
  int r = tid >> 4, k = tid & 15;
  float w = W[tid];
  __hip_bfloat16 h = __float2bfloat16(w);
  __hip_bfloat16 l = __float2bfloat16(w - __bfloat162float(h));
  size_t base = (size_t)r*64;
  P[base + k] = h; P[base + 16 + k] = h; P[base + 32 + k] = l;
  P[base + 48 + k] = __float2bfloat16(0.0f);
}
// x (N,T,16) -> Xp (N,T,64): [hi | lo | hi | 0]
__global__ __launch_bounds__(256) void pack_x(const float* __restrict__ x,
                                              __hip_bfloat16* __restrict__ Xp){
  int tid = blockIdx.x*256 + threadIdx.x;   // 2048 blocks
  const float* xr = x + (size_t)tid*16;
  __hip_bfloat16* o = Xp + (size_t)tid*64;
  for (int k=0;k<16;k++){
    float v = xr[k];
    __hip_bfloat16 h = __float2bfloat16(v);
    __hip_bfloat16 l = __float2bfloat16(v - __bfloat162float(h));
    o[k] = h; o[16+k] = l; o[32+k] = h; o[48+k] = __float2bfloat16(0.0f);
  }
}
__global__ __launch_bounds__(256) void recon_nf(const __hip_bfloat16* __restrict__ hi,
    const __hip_bfloat16* __restrict__ lo, float* __restrict__ nf){
  int tid = blockIdx.x*256 + threadIdx.x;
  nf[tid] = __bfloat162float(hi[tid]) + __bfloat162float(lo[tid]);
}

// ---------------- fused two-layer skewed LSTM step (MFMA bf16x3) ----------------
// Launch t: blocks [0,256) layer0 step t; [256,512) layer1 step t-1.
// Block: 128 m x 16 j x 4 gates, 4 waves (wave = 32 m-rows).
// Chunk table built once per block (active chunks only). A-hi chunks are
// MFMA'd against BOTH B-hi and B-lo; A-lo chunks against B-hi only.
// One barrier per chunk, stage-ahead double buffer.
__global__ __launch_bounds__(256, 2) void lstm2_step(
    int t,
    const __hip_bfloat16* __restrict__ Xp,
    const __hip_bfloat16* __restrict__ P0ih,
    const __hip_bfloat16* __restrict__ P0hh,
    const __hip_bfloat16* __restrict__ P1ih,
    const __hip_bfloat16* __restrict__ P1hh,
    const float* __restrict__ bih0, const float* __restrict__ bhh0,
    const float* __restrict__ bih1, const float* __restrict__ bhh1,
    const __hip_bfloat16* __restrict__ h0p_hi, const __hip_bfloat16* __restrict__ h0p_lo,
    __hip_bfloat16* __restrict__ h0o_hi, __hip_bfloat16* __restrict__ h0o_lo,
    const __hip_bfloat16* __restrict__ h1p_hi, const __hip_bfloat16* __restrict__ h1p_lo,
    __hip_bfloat16* __restrict__ h1o_hi, __hip_bfloat16* __restrict__ h1o_lo,
    float* __restrict__ c0, float* __restrict__ c1)
{
  __shared__ __align__(16) __hip_bfloat16 Ast[2][128*64];    // 2 x 16KB
  __shared__ __align__(16) __hip_bfloat16 Bst[2][2][64*64];  // [buf][hi/lo] 4 x 8KB
  const int bid = blockIdx.x;
  const bool isL0 = bid < 256;
  if (isL0 && t >= TT) return;
  if (!isL0 && t == 0) return;
  const int idx = bid & 255;
  const int m0 = (idx >> 4) << 7;
  const int j0 = (idx & 15) << 4;
  const int lane = threadIdx.x & 63, wv = threadIdx.x >> 6;
  const int rr = lane >> 3;
  const int sw8 = (((lane & 7) ^ rr) << 3);     // source-side XOR swizzle
  const int frow = lane & 15;

  // ---- chunk table (k-column offset folded into base pointers) ----
  const __hip_bfloat16* CA[16];   // A base (+kb)
  const __hip_bfloat16* CB1[16];  // B-hi base (+kb)
  const __hip_bfloat16* CB2[16];  // B-lo base (+kb) or null
  size_t Clda[16];
  int nc = 0;
  if (isL0){
    if (t != 0){
      #pragma unroll
      for (int c=0;c<4;c++){ CA[nc]=h0p_hi+(c<<6); Clda[nc]=256;
        CB1[nc]=P0hh+(c<<6); CB2[nc]=P0hh+256+(c<<6); nc++; }
      #pragma unroll
      for (int c=0;c<4;c++){ CA[nc]=h0p_lo+(c<<6); Clda[nc]=256;
        CB1[nc]=P0hh+(c<<6); CB2[nc]=nullptr; nc++; }
    }
    CA[nc]=Xp+(size_t)t*64; Clda[nc]=(size_t)TT*64; CB1[nc]=P0ih; CB2[nc]=nullptr; nc++;
  } else {
    #pragma unroll
    for (int c=0;c<4;c++){ CA[nc]=h0p_hi+(c<<6); Clda[nc]=256;
      CB1[nc]=P1ih+(c<<6); CB2[nc]=P1ih+256+(c<<6); nc++; }
    #pragma unroll
    for (int c=0;c<4;c++){ CA[nc]=h0p_lo+(c<<6); Clda[nc]=256;
      CB1[nc]=P1ih+(c<<6); CB2[nc]=nullptr; nc++; }
    if (t >= 2){
      #pragma unroll
      for (int c=0;c<4;c++){ CA[nc]=h1p_hi+(c<<6); Clda[nc]=256;
        CB1[nc]=P1hh+(c<<6); CB2[nc]=P1hh+256+(c<<6); nc++; }
      #pragma unroll
      for (int c=0;c<4;c++){ CA[nc]=h1p_lo+(c<<6); Clda[nc]=256;
        CB1[nc]=P1hh+(c<<6); CB2[nc]=nullptr; nc++; }
    }
  }
  // B leading dims: P* weight tables are 512-wide, P0ih is 64-wide.
  const size_t ldb_w = 512;

  f32x4 acc[2][4] = {};                 // [m-subtile][gate]

  // ---- stage chunk c into buffer nb ----
  auto stage = [&](int c, int nb){
    const size_t lda = Clda[c];
    const size_t ldb = (CB1[c] == P0ih) ? (size_t)64 : ldb_w;
    const __hip_bfloat16* Ab = CA[c] + (size_t)(m0 + wv*32 + rr)*lda + sw8;
    __hip_bfloat16* Ad = &Ast[nb][(wv*32)*64];
    #pragma unroll
    for (int c2=0;c2<4;c2++) glds16(Ab + (size_t)(c2*8)*lda, Ad + c2*8*64);
    const __hip_bfloat16* Bb1 = CB1[c] + (size_t)(wv*256 + j0 + rr)*ldb + sw8;
    __hip_bfloat16* Bd1 = &Bst[nb][0][(wv<<4)*64];
    glds16(Bb1, Bd1); glds16(Bb1 + (size_t)8*ldb, Bd1 + 8*64);
    if (CB2[c]){
      const __hip_bfloat16* Bb2 = CB2[c] + (size_t)(wv*256 + j0 + rr)*ldb + sw8;
      __hip_bfloat16* Bd2 = &Bst[nb][1][(wv<<4)*64];
      glds16(Bb2, Bd2); glds16(Bb2 + (size_t)8*ldb, Bd2 + 8*64);
    }
  };

  stage(0, 0);
  __syncthreads();
  for (int c=0; c<nc; ++c){
    if (c+1 < nc) stage(c+1, (c+1)&1);  // prefetch in flight during compute
    const int nb = c&1;
    const bool hasB2 = (CB2[c] != nullptr);
    #pragma unroll
    for (int w2=0; w2<2; ++w2){
      const int sl8 = ((((w2<<2) + (lane>>4)) ^ (lane&7)) << 3);
      short8 a0 = *(const short8*)&Ast[nb][(wv*32 +      frow)*64 + sl8];
      short8 a1 = *(const short8*)&Ast[nb][(wv*32 + 16 + frow)*64 + sl8];
      #pragma unroll
      for (int g=0; g<4; ++g){
        short8 b1 = *(const short8*)&Bst[nb][0][((g<<4) + frow)*64 + sl8];
        acc[0][g] = __builtin_amdgcn_mfma_f32_16x16x32_bf16(a0, b1, acc[0][g], 0,0,0);
        acc[1][g] = __builtin_amdgcn_mfma_f32_16x16x32_bf16(a1, b1, acc[1][g], 0,0,0);
      }
      if (hasB2){
        #pragma unroll
        for (int g=0; g<4; ++g){
          short8 b2 = *(const short8*)&Bst[nb][1][((g<<4) + frow)*64 + sl8];
          acc[0][g] = __builtin_amdgcn_mfma_f32_16x16x32_bf16(a0, b2, acc[0][g], 0,0,0);
          acc[1][g] = __builtin_amdgcn_mfma_f32_16x16x32_bf16(a1, b2, acc[1][g], 0,0,0);
        }
      }
    }
    __syncthreads();
  }

  // epilogue: lane holds all 4 gates. C map: col=lane&15, row=(lane>>4)*4+r
  const int j = j0 + frow;
  const float* bih = isL0 ? bih0 : bih1;
  const float* bhh = isL0 ? bhh0 : bhh1;
  float* cst = isL0 ? c0 : c1;
  __hip_bfloat16* ohi = isL0 ? h0o_hi : h1o_hi;
  __hip_bfloat16* olo = isL0 ? h0o_lo : h1o_lo;
  const int first = isL0 ? (t==0) : (t==1);
  const float b0 = bih[j]        + bhh[j];
  const float b1 = bih[HH + j]   + bhh[HH + j];
  const float b2 = bih[2*HH + j] + bhh[2*HH + j];
  const float b3 = bih[3*HH + j] + bhh[3*HH + j];
  #pragma unroll
  for (int mt=0; mt<2; ++mt){
    const int mrb = m0 + wv*32 + mt*16 + ((lane>>4)<<2);
    #pragma unroll
    for (int r=0; r<4; ++r){
      const size_t mi = (size_t)(mrb + r)*HH + j;
      float gi = acc[mt][0][r] + b0;
      float gf = acc[mt][1][r] + b1;
      float gg = acc[mt][2][r] + b2;
      float go = acc[mt][3][r] + b3;
      float cold = first ? 0.f : cst[mi];
      float cn = sigmoidf_(gf)*cold + sigmoidf_(gi)*tanhf(gg);
      float hv = sigmoidf_(go)*tanhf(cn);
      cst[mi] = cn;
      __hip_bfloat16 hb = __float2bfloat16(hv);
      ohi[mi] = hb;
      olo[mi] = __float2bfloat16(hv - __bfloat162float(hb));
    }
  }
}

// ---------------- fp32 tail (unchanged, proven) ----------------
__global__ __launch_bounds__(256) void gemm_nn(
    float* __restrict__ C, const float* __restrict__ A, const float* __restrict__ B,
    int K, int lda, int ldb, int ldc, int relu)
{
  __shared__ float As_[16][68];
  __shared__ float Bs_[16][64];
  float acc[4][4] = {};
  const int tx = threadIdx.x;
  const int m0 = blockIdx.y<<6, n0 = blockIdx.x<<6;
  const int am = tx>>2, ak = (tx&3)<<2;
  const int bk = tx>>4, bn = (tx&15)<<2;
  const int mm = (tx>>4)<<2, nc = (tx&15)<<2;
  for (int kb=0; kb<K; kb+=16){
    float4 av = *reinterpret_cast<const float4*>(A + (size_t)(m0+am)*lda + kb + ak);
    As_[ak][am]=av.x; As_[ak+1][am]=av.y; As_[ak+2][am]=av.z; As_[ak+3][am]=av.w;
    *reinterpret_cast<float4*>(&Bs_[bk][bn]) =
      *reinterpret_cast<const float4*>(B + (size_t)(kb+bk)*ldb + n0 + bn);
    __syncthreads();
    #pragma unroll
    for (int k=0;k<16;k++){
      float4 a4 = *reinterpret_cast<const float4*>(&As_[k][mm]);
      float4 b4 = *reinterpret_cast<const float4*>(&Bs_[k][nc]);
      acc[0][0]=fmaf(a4.x,b4.x,acc[0][0]); acc[0][1]=fmaf(a4.x,b4.y,acc[0][1]);
      acc[0][2]=fmaf(a4.x,b4.z,acc[0][2]); acc[0][3]=fmaf(a4.x,b4.w,acc[0][3]);
      acc[1][0]=fmaf(a4.y,b4.x,acc[1][0]); acc[1][1]=fmaf(a4.y,b4.y,acc[1][1]);
      acc[1][2]=fmaf(a4.y,b4.z,acc[1][2]); acc[1][3]=fmaf(a4.y,b4.w,acc[1][3]);
      acc[2][0]=fmaf(a4.z,b4.x,acc[2][0]); acc[2][1]=fmaf(a4.z,b4.y,acc[2][1]);
      acc[2][2]=fmaf(a4.z,b4.z,acc[2][2]); acc[2][3]=fmaf(a4.z,b4.w,acc[2][3]);
      acc[3][0]=fmaf(a4.w,b4.x,acc[3][0]); acc[3][1]=fmaf(a4.w,b4.y,acc[3][1]);
      acc[3][2]=fmaf(a4.w,b4.z,acc[3][2]); acc[3][3]=fmaf(a4.w,b4.w,acc[3][3]);
    }
    __syncthreads();
  }
  #pragma unroll
  for (int r=0;r<4;r++){
    float4 v = make_float4(acc[r][0],acc[r][1],acc[r][2],acc[r][3]);
    if (relu){ v.x=fmaxf(v.x,0.f); v.y=fmaxf(v.y,0.f); v.z=fmaxf(v.z,0.f); v.w=fmaxf(v.w,0.f); }
    *reinterpret_cast<float4*>(C + (size_t)(m0+mm+r)*ldc + n0 + nc) = v;
  }
}

__global__ __launch_bounds__(256) void gemm_nt(
    float* __restrict__ C, const float* __restrict__ A, const float* __restrict__ B,
    int K, int lda, int ldb, int ldc)
{
  __shared__ float As_[16][68];
  __shared__ float Bs_[16][68];
  float acc[4][4] = {};
  const int tx = threadIdx.x;
  const int m0 = blockIdx.y<<6, n0 = blockIdx.x<<6;
  const int am = tx>>2, ak = (tx&3)<<2;
  const int mm = (tx>>4)<<2, nc = (tx&15)<<2;
  for (int kb=0; kb<K; kb+=16){
    float4 av = *reinterpret_cast<const float4*>(A + (size_t)(m0+am)*lda + kb + ak);
    As_[ak][am]=av.x; As_[ak+1][am]=av.y; As_[ak+2][am]=av.z; As_[ak+3][am]=av.w;
    float4 bv = *reinterpret_cast<const float4*>(B + (size_t)(n0+am)*ldb + kb + ak);
    Bs_[ak][am]=bv.x; Bs_[ak+1][am]=bv.y; Bs_[ak+2][am]=bv.z; Bs_[ak+3][am]=bv.w;
    __syncthreads();
    #pragma unroll
    for (int k=0;k<16;k++){
      float4 a4 = *reinterpret_cast<const float4*>(&As_[k][mm]);
      float4 b4 = *reinterpret_cast<const float4*>(&Bs_[k][nc]);
      acc[0][0]=fmaf(a4.x,b4.x,acc[0][0]); acc[0][1]=fmaf(a4.x,b4.y,acc[0][1]);
      acc[0][2]=fmaf(a4.x,b4.z,acc[0][2]); acc[0][3]=fmaf(a4.x,b4.w,acc[0][3]);
      acc[1][0]=fmaf(a4.y,b4.x,acc[1][0]); acc[1][1]=fmaf(a4.y,b4.y,acc[1][1]);
      acc[1][2]=fmaf(a4.y,b4.z,acc[1][2]); acc[1][3]=fmaf(a4.y,b4.w,acc[1][3]);
      acc[2][0]=fmaf(a4.z,b4.x,acc[2][0]); acc[2][1]=fmaf(a4.z,b4.y,acc[2][1]);
      acc[2][2]=fmaf(a4.z,b4.z,acc[2][2]); acc[2][3]=fmaf(a4.z,b4.w,acc[2][3]);
      acc[3][0]=fmaf(a4.w,b4.x,acc[3][0]); acc[3][1]=fmaf(a4.w,b4.y,acc[3][1]);
      acc[3][2]=fmaf(a4.w,b4.z,acc[3][2]); acc[3][3]=fmaf(a4.w,b4.w,acc[3][3]);
    }
    __syncthreads();
  }
  #pragma unroll
  for (int r=0;r<4;r++){
    float4 v = make_float4(acc[r][0],acc[r][1],acc[r][2],acc[r][3]);
    *reinterpret_cast<float4*>(C + (size_t)(m0+mm+r)*ldc + n0 + nc) = v;
  }
}

__global__ __launch_bounds__(256) void rowstat(const float* __restrict__ nf,
    float* __restrict__ xc, float* __restrict__ dvec)
{
  __shared__ float red[256];
  int n = blockIdx.x, tx = threadIdx.x;
  float v = nf[(size_t)n*HH + tx];
  red[tx] = v; __syncthreads();
  for (int s=128; s>0; s>>=1){ if (tx<s) red[tx]+=red[tx+s]; __syncthreads(); }
  float mean = red[0] * (1.0f/HH);
  __syncthreads();
  float d = v - mean;
  xc[(size_t)n*HH + tx] = d;
  red[tx] = d*d; __syncthreads();
  for (int s=128; s>0; s>>=1){ if (tx<s) red[tx]+=red[tx+s]; __syncthreads(); }
  if (tx==0) dvec[n] = sqrtf(red[0]);
}

__global__ __launch_bounds__(256) void rowsum(const float* __restrict__ cov,
    const float* __restrict__ dvec, float* __restrict__ dinv)
{
  __shared__ float red[256];
  int i = blockIdx.x, tx = threadIdx.x;
  float di = dvec[i];
  float s = 0.f;
  for (int jj=tx; jj<NN; jj+=256){
    float r = cov[(size_t)i*NN + jj] / (di * dvec[jj]);
    if (r != r) r = 0.f; else r = fminf(1.f, fmaxf(-1.f, r));
    s += r;
  }
  red[tx]=s; __syncthreads();
  for (int st=128; st>0; st>>=1){ if (tx<st) red[tx]+=red[tx+st]; __syncthreads(); }
  if (tx==0){
    float tot = red[0] + 1.0f;
    float p = powf(tot, -0.5f);
    if (isinf(p)) p = 0.f;
    dinv[i] = p;
  }
}

__global__ __launch_bounds__(256) void adjnorm(float* __restrict__ cov,
    const float* __restrict__ dvec, const float* __restrict__ dinv)
{
  size_t idx = (size_t)blockIdx.x*256 + threadIdx.x;
  int i = (int)(idx >> 11), jj = (int)(idx & (NN-1));
  float r = cov[idx] / (dvec[i]*dvec[jj]);
  if (r != r) r = 0.f; else r = fminf(1.f, fmaxf(-1.f, r));
  if (i==jj) r += 1.f;
  cov[idx] = dinv[i]*r*dinv[jj];
}

__global__ __launch_bounds__(128) void predk(const float* __restrict__ G2,
    const float* __restrict__ Wfc, const float* __restrict__ bfc, float* __restrict__ out)
{
  int n = blockIdx.x, tx = threadIdx.x;
  float v = G2[(size_t)n*128 + tx] * Wfc[tx];
  for (int off=32; off>0; off>>=1) v += __shfl_down(v, off);
  __shared__ float p[2];
  if ((tx&63)==0) p[tx>>6] = v;
  __syncthreads();
  if (tx==0) out[n] = p[0] + p[1] + bfc[0];
}

extern "C" void kernel_launch(void* const* d_in, const int* in_sizes, int n_in,
                              void* d_out, int out_size, void* d_ws, size_t ws_size,
                              hipStream_t stream)
{
  const float* x    = (const float*)d_in[0];
  const float* Wih0 = (const float*)d_in[1];
  const float* Whh0 = (const float*)d_in[2];
  const float* bih0 = (const float*)d_in[3];
  const float* bhh0 = (const float*)d_in[4];
  const float* Wih1 = (const float*)d_in[5];
  const float* Whh1 = (const float*)d_in[6];
  const float* bih1 = (const float*)d_in[7];
  const float* bhh1 = (const float*)d_in[8];
  const float* Wg1  = (const float*)d_in[9];
  const float* Wg2  = (const float*)d_in[10];
  const float* Wfc  = (const float*)d_in[11];
  const float* bfc  = (const float*)d_in[12];
  float* out = (float*)d_out;

  char* w = (char*)d_ws;
  auto alloc = [&](size_t bytes){ char* p = w; w += (bytes + 255) & ~(size_t)255; return p; };
  __hip_bfloat16* Xp   = (__hip_bfloat16*)alloc((size_t)NN*TT*64*2);
  __hip_bfloat16* P0hh = (__hip_bfloat16*)alloc((size_t)1024*512*2);
  __hip_bfloat16* P1ih = (__hip_bfloat16*)alloc((size_t)1024*512*2);
  __hip_bfloat16* P1hh = (__hip_bfloat16*)alloc((size_t)1024*512*2);
  __hip_bfloat16* P0ih = (__hip_bfloat16*)alloc((size_t)1024*64*2);
  __hip_bfloat16 *H0hi[2], *H0lo[2], *H1hi[2], *H1lo[2];
  for (int i=0;i<2;i++){ H0hi[i]=(__hip_bfloat16*)alloc((size_t)NN*HH*2);
                         H0lo[i]=(__hip_bfloat16*)alloc((size_t)NN*HH*2); }
  for (int i=0;i<2;i++){ H1hi[i]=(__hip_bfloat16*)alloc((size_t)NN*HH*2);
                         H1lo[i]=(__hip_bfloat16*)alloc((size_t)NN*HH*2); }
  float* c0   = (float*)alloc((size_t)NN*HH*4);
  float* c1   = (float*)alloc((size_t)NN*HH*4);
  float* nf   = (float*)alloc((size_t)NN*HH*4);
  float* xc   = (float*)alloc((size_t)NN*HH*4);
  float* cov  = (float*)alloc((size_t)NN*NN*4);
  float* t1   = (float*)alloc((size_t)NN*HH*4);
  float* G1   = (float*)alloc((size_t)NN*HH*4);
  float* t2   = (float*)alloc((size_t)NN*128*4);
  float* G2   = (float*)alloc((size_t)NN*128*4);
  float* dvec = (float*)alloc((size_t)NN*4);
  float* dinv = (float*)alloc((size_t)NN*4);

  hipLaunchKernelGGL(pack_w2, dim3(1024), dim3(256), 0, stream, Whh0, P0hh);
  hipLaunchKernelGGL(pack_w2, dim3(1024), dim3(256), 0, stream, Wih1, P1ih);
  hipLaunchKernelGGL(pack_w2, dim3(1024), dim3(256), 0, stream, Whh1, P1hh);
  hipLaunchKernelGGL(pack_w0, dim3(64),   dim3(256), 0, stream, Wih0, P0ih);
  hipLaunchKernelGGL(pack_x,  dim3(2048), dim3(256), 0, stream, x, Xp);

  // skewed recurrence: launch t runs L0(t) and L1(t-1)
  for (int t=0; t<=TT; ++t){
    const __hip_bfloat16 *h0p_hi = H0hi[(t+1)&1], *h0p_lo = H0lo[(t+1)&1];
    __hip_bfloat16 *h0o_hi = H0hi[t&1], *h0o_lo = H0lo[t&1];
    const __hip_bfloat16 *h1p_hi = H1hi[t&1], *h1p_lo = H1lo[t&1];
    __hip_bfloat16 *h1o_hi = H1hi[(t+1)&1], *h1o_lo = H1lo[(t+1)&1];
    hipLaunchKernelGGL(lstm2_step, dim3(512), dim3(256), 0, stream,
        t, Xp, P0ih, P0hh, P1ih, P1hh, bih0, bhh0, bih1, bhh1,
        h0p_hi, h0p_lo, h0o_hi, h0o_lo, h1p_hi, h1p_lo, h1o_hi, h1o_lo, c0, c1);
  }
  // final h1 (step 255, written at launch t=256) lives in H1[1]
  hipLaunchKernelGGL(recon_nf, dim3(2048), dim3(256), 0, stream, H1hi[1], H1lo[1], nf);

  hipLaunchKernelGGL(rowstat, dim3(NN), dim3(256), 0, stream, nf, xc, dvec);
  hipLaunchKernelGGL(gemm_nt, dim3(NN/64, NN/64), dim3(256), 0, stream,
      cov, xc, xc, HH, HH, HH, NN);
  hipLaunchKernelGGL(rowsum, dim3(NN), dim3(256), 0, stream, cov, dvec, dinv);
  hipLaunchKernelGGL(adjnorm, dim3(NN*NN/256), dim3(256), 0, stream, cov, dvec, dinv);

  hipLaunchKernelGGL(gemm_nn, dim3(HH/64, NN/64), dim3(256), 0, stream,
      t1, nf, Wg1, HH, HH, HH, HH, 0);
  hipLaunchKernelGGL(gemm_nn, dim3(HH/64, NN/64), dim3(256), 0, stream,
      G1, cov, t1, NN, NN, HH, HH, 1);
  hipLaunchKernelGGL(gemm_nn, dim3(128/64, NN/64), dim3(256), 0, stream,
      t2, G1, Wg2, HH, HH, 128, 128, 0);
  hipLaunchKernelGGL(gemm_nn, dim3(128/64, NN/64), dim3(256), 0, stream,
      G2, cov, t2, NN, NN, 128, 128, 0);
  hipLaunchKernelGGL(predk, dim3(NN), dim3(128), 0, stream, G2, Wfc, bfc, out);
}

// Round 8
// 6262.267 us; speedup vs baseline: 4.0742x; 1.7213x over previous
//
#include <hip/hip_runtime.h>
#include <hip/hip_bf16.h>
#include <cmath>

#define NN 2048
#define TT 256
#define DD 16
#define HH 256

typedef __attribute__((ext_vector_type(8))) short short8;
typedef __attribute__((ext_vector_type(4))) float f32x4;

__device__ __forceinline__ float sigmoidf_(float x){ return 1.0f/(1.0f+expf(-x)); }

// async 16B/lane global->LDS (LDS dest wave-uniform base; HW adds lane*16)
__device__ __forceinline__ void glds16(const __hip_bfloat16* g, __hip_bfloat16* l){
  __builtin_amdgcn_global_load_lds(
      (const __attribute__((address_space(1))) void*)g,
      (__attribute__((address_space(3))) void*)l, 16, 0, 0);
}

// ---------------- packing ----------------
// W (1024x256) -> P (1024x512): [hi | lo]
__global__ __launch_bounds__(256) void pack_w2(const float* __restrict__ W,
                                               __hip_bfloat16* __restrict__ P){
  int tid = blockIdx.x*256 + threadIdx.x;   // 1024 blocks
  int r = tid >> 8, k = tid & 255;
  float w = W[tid];
  __hip_bfloat16 h = __float2bfloat16(w);
  __hip_bfloat16 l = __float2bfloat16(w - __bfloat162float(h));
  size_t base = (size_t)r*512;
  P[base + k] = h; P[base + 256 + k] = l;
}
// Wih0 (1024 x 16) -> (1024 x 64): [hi | hi | lo | 0] (pairs with x [hi|lo|hi|0])
__global__ __launch_bounds__(256) void pack_w0(const float* __restrict__ W,
                                               __hip_bfloat16* __restrict__ P){
  int tid = blockIdx.x*256 + threadIdx.x;   // 64 blocks
  int r = tid >> 4, k = tid & 15;
  float w = W[tid];
  __hip_bfloat16 h = __float2bfloat16(w);
  __hip_bfloat16 l = __float2bfloat16(w - __bfloat162float(h));
  size_t base = (size_t)r*64;
  P[base + k] = h; P[base + 16 + k] = h; P[base + 32 + k] = l;
  P[base + 48 + k] = __float2bfloat16(0.0f);
}
// x (N,T,16) -> Xp (N,T,64): [hi | lo | hi | 0]
__global__ __launch_bounds__(256) void pack_x(const float* __restrict__ x,
                                              __hip_bfloat16* __restrict__ Xp){
  int tid = blockIdx.x*256 + threadIdx.x;   // 2048 blocks
  const float* xr = x + (size_t)tid*16;
  __hip_bfloat16* o = Xp + (size_t)tid*64;
  for (int k=0;k<16;k++){
    float v = xr[k];
    __hip_bfloat16 h = __float2bfloat16(v);
    __hip_bfloat16 l = __float2bfloat16(v - __bfloat162float(h));
    o[k] = h; o[16+k] = l; o[32+k] = h; o[48+k] = __float2bfloat16(0.0f);
  }
}
__global__ __launch_bounds__(256) void recon_nf(const __hip_bfloat16* __restrict__ hi,
    const __hip_bfloat16* __restrict__ lo, float* __restrict__ nf){
  int tid = blockIdx.x*256 + threadIdx.x;
  nf[tid] = __bfloat162float(hi[tid]) + __bfloat162float(lo[tid]);
}

// ---------------- GEMM segments (R3 structure, dual-B variant) ----------------
// Block tile: 128 m x 16 j x 4 gates. 4 waves; wave stages its 32 m-rows of A
// and gate-group wv's 16 rows of B. Two barriers per k64 chunk (proven R3 shape).
// Dual: A-hi chunk MFMA'd against both B-hi and B-lo columns of packed [hi|lo] W.
__device__ __forceinline__ void mm_dual(
    const __hip_bfloat16* __restrict__ A, size_t lda,
    const __hip_bfloat16* __restrict__ Bhi, const __hip_bfloat16* __restrict__ Blo,
    size_t ldb, int Klen,
    int m0, int j0, int wv, int lane, int rr, int sw8, int frow,
    f32x4 (&acc)[2][4],
    __hip_bfloat16* As, __hip_bfloat16* BsHi, __hip_bfloat16* BsLo)
{
  for (int kb=0; kb<Klen; kb+=64){
    const __hip_bfloat16* Ab = A + (size_t)(m0 + wv*32 + rr)*lda + kb + sw8;
    __hip_bfloat16* Ad = As + (wv*32)*64;
    #pragma unroll
    for (int c2=0;c2<4;c2++) glds16(Ab + (size_t)(c2*8)*lda, Ad + c2*8*64);
    const __hip_bfloat16* Bb1 = Bhi + (size_t)(wv*256 + j0 + rr)*ldb + kb + sw8;
    __hip_bfloat16* Bd1 = BsHi + (wv<<4)*64;
    glds16(Bb1, Bd1); glds16(Bb1 + (size_t)8*ldb, Bd1 + 8*64);
    const __hip_bfloat16* Bb2 = Blo + (size_t)(wv*256 + j0 + rr)*ldb + kb + sw8;
    __hip_bfloat16* Bd2 = BsLo + (wv<<4)*64;
    glds16(Bb2, Bd2); glds16(Bb2 + (size_t)8*ldb, Bd2 + 8*64);
    __syncthreads();
    #pragma unroll
    for (int w2=0; w2<2; ++w2){
      const int sl8 = ((((w2<<2) + (lane>>4)) ^ (lane&7)) << 3);
      short8 a0 = *(const short8*)&As[(wv*32 +      frow)*64 + sl8];
      short8 a1 = *(const short8*)&As[(wv*32 + 16 + frow)*64 + sl8];
      #pragma unroll
      for (int g=0; g<4; ++g){
        short8 b1 = *(const short8*)&BsHi[((g<<4) + frow)*64 + sl8];
        acc[0][g] = __builtin_amdgcn_mfma_f32_16x16x32_bf16(a0, b1, acc[0][g], 0,0,0);
        acc[1][g] = __builtin_amdgcn_mfma_f32_16x16x32_bf16(a1, b1, acc[1][g], 0,0,0);
        short8 b2 = *(const short8*)&BsLo[((g<<4) + frow)*64 + sl8];
        acc[0][g] = __builtin_amdgcn_mfma_f32_16x16x32_bf16(a0, b2, acc[0][g], 0,0,0);
        acc[1][g] = __builtin_amdgcn_mfma_f32_16x16x32_bf16(a1, b2, acc[1][g], 0,0,0);
      }
    }
    __syncthreads();
  }
}

__device__ __forceinline__ void mm_single(
    const __hip_bfloat16* __restrict__ A, size_t lda,
    const __hip_bfloat16* __restrict__ B, size_t ldb, int Klen,
    int m0, int j0, int wv, int lane, int rr, int sw8, int frow,
    f32x4 (&acc)[2][4],
    __hip_bfloat16* As, __hip_bfloat16* BsHi)
{
  for (int kb=0; kb<Klen; kb+=64){
    const __hip_bfloat16* Ab = A + (size_t)(m0 + wv*32 + rr)*lda + kb + sw8;
    __hip_bfloat16* Ad = As + (wv*32)*64;
    #pragma unroll
    for (int c2=0;c2<4;c2++) glds16(Ab + (size_t)(c2*8)*lda, Ad + c2*8*64);
    const __hip_bfloat16* Bb1 = B + (size_t)(wv*256 + j0 + rr)*ldb + kb + sw8;
    __hip_bfloat16* Bd1 = BsHi + (wv<<4)*64;
    glds16(Bb1, Bd1); glds16(Bb1 + (size_t)8*ldb, Bd1 + 8*64);
    __syncthreads();
    #pragma unroll
    for (int w2=0; w2<2; ++w2){
      const int sl8 = ((((w2<<2) + (lane>>4)) ^ (lane&7)) << 3);
      short8 a0 = *(const short8*)&As[(wv*32 +      frow)*64 + sl8];
      short8 a1 = *(const short8*)&As[(wv*32 + 16 + frow)*64 + sl8];
      #pragma unroll
      for (int g=0; g<4; ++g){
        short8 b1 = *(const short8*)&BsHi[((g<<4) + frow)*64 + sl8];
        acc[0][g] = __builtin_amdgcn_mfma_f32_16x16x32_bf16(a0, b1, acc[0][g], 0,0,0);
        acc[1][g] = __builtin_amdgcn_mfma_f32_16x16x32_bf16(a1, b1, acc[1][g], 0,0,0);
      }
    }
    __syncthreads();
  }
}

// ---------------- fused two-layer skewed LSTM step (MFMA bf16x3) ----------------
// Launch t: blocks [0,256) layer0 step t; [256,512) layer1 step t-1.
__global__ __launch_bounds__(256, 2) void lstm2_step(
    int t,
    const __hip_bfloat16* __restrict__ Xp,
    const __hip_bfloat16* __restrict__ P0ih,
    const __hip_bfloat16* __restrict__ P0hh,
    const __hip_bfloat16* __restrict__ P1ih,
    const __hip_bfloat16* __restrict__ P1hh,
    const float* __restrict__ bih0, const float* __restrict__ bhh0,
    const float* __restrict__ bih1, const float* __restrict__ bhh1,
    const __hip_bfloat16* __restrict__ h0p_hi, const __hip_bfloat16* __restrict__ h0p_lo,
    __hip_bfloat16* __restrict__ h0o_hi, __hip_bfloat16* __restrict__ h0o_lo,
    const __hip_bfloat16* __restrict__ h1p_hi, const __hip_bfloat16* __restrict__ h1p_lo,
    __hip_bfloat16* __restrict__ h1o_hi, __hip_bfloat16* __restrict__ h1o_lo,
    float* __restrict__ c0, float* __restrict__ c1)
{
  __shared__ __align__(16) __hip_bfloat16 As[128*64];      // 16 KB
  __shared__ __align__(16) __hip_bfloat16 BsHi[64*64];     // 8 KB
  __shared__ __align__(16) __hip_bfloat16 BsLo[64*64];     // 8 KB
  const int bid = blockIdx.x;
  const bool isL0 = bid < 256;
  if (isL0 && t >= TT) return;
  if (!isL0 && t == 0) return;
  const int idx = bid & 255;
  const int m0 = (idx >> 4) << 7;
  const int j0 = (idx & 15) << 4;
  const int lane = threadIdx.x & 63, wv = threadIdx.x >> 6;
  const int rr = lane >> 3;
  const int sw8 = (((lane & 7) ^ rr) << 3);     // source-side XOR swizzle
  const int frow = lane & 15;

  f32x4 acc[2][4] = {};                 // [m-subtile][gate]

  if (isL0){
    if (t != 0){
      mm_dual  (h0p_hi, 256, P0hh, P0hh+256, 512, 256,
                m0, j0, wv, lane, rr, sw8, frow, acc, As, BsHi, BsLo);
      mm_single(h0p_lo, 256, P0hh, 512, 256,
                m0, j0, wv, lane, rr, sw8, frow, acc, As, BsHi);
    }
    mm_single(Xp + (size_t)t*64, (size_t)TT*64, P0ih, 64, 64,
              m0, j0, wv, lane, rr, sw8, frow, acc, As, BsHi);
  } else {
    mm_dual  (h0p_hi, 256, P1ih, P1ih+256, 512, 256,
              m0, j0, wv, lane, rr, sw8, frow, acc, As, BsHi, BsLo);
    mm_single(h0p_lo, 256, P1ih, 512, 256,
              m0, j0, wv, lane, rr, sw8, frow, acc, As, BsHi);
    if (t != 1){
      mm_dual  (h1p_hi, 256, P1hh, P1hh+256, 512, 256,
                m0, j0, wv, lane, rr, sw8, frow, acc, As, BsHi, BsLo);
      mm_single(h1p_lo, 256, P1hh, 512, 256,
                m0, j0, wv, lane, rr, sw8, frow, acc, As, BsHi);
    }
  }

  // epilogue: lane holds all 4 gates. C map: col=lane&15, row=(lane>>4)*4+r
  const int j = j0 + frow;
  const float* bih = isL0 ? bih0 : bih1;
  const float* bhh = isL0 ? bhh0 : bhh1;
  float* cst = isL0 ? c0 : c1;
  __hip_bfloat16* ohi = isL0 ? h0o_hi : h1o_hi;
  __hip_bfloat16* olo = isL0 ? h0o_lo : h1o_lo;
  const int first = isL0 ? (t==0) : (t==1);
  const float b0 = bih[j]        + bhh[j];
  const float b1 = bih[HH + j]   + bhh[HH + j];
  const float b2 = bih[2*HH + j] + bhh[2*HH + j];
  const float b3 = bih[3*HH + j] + bhh[3*HH + j];
  #pragma unroll
  for (int mt=0; mt<2; ++mt){
    const int mrb = m0 + wv*32 + mt*16 + ((lane>>4)<<2);
    #pragma unroll
    for (int r=0; r<4; ++r){
      const size_t mi = (size_t)(mrb + r)*HH + j;
      float gi = acc[mt][0][r] + b0;
      float gf = acc[mt][1][r] + b1;
      float gg = acc[mt][2][r] + b2;
      float go = acc[mt][3][r] + b3;
      float cold = first ? 0.f : cst[mi];
      float cn = sigmoidf_(gf)*cold + sigmoidf_(gi)*tanhf(gg);
      float hv = sigmoidf_(go)*tanhf(cn);
      cst[mi] = cn;
      __hip_bfloat16 hb = __float2bfloat16(hv);
      ohi[mi] = hb;
      olo[mi] = __float2bfloat16(hv - __bfloat162float(hb));
    }
  }
}

// ---------------- fp32 tail (unchanged, proven) ----------------
__global__ __launch_bounds__(256) void gemm_nn(
    float* __restrict__ C, const float* __restrict__ A, const float* __restrict__ B,
    int K, int lda, int ldb, int ldc, int relu)
{
  __shared__ float As_[16][68];
  __shared__ float Bs_[16][64];
  float acc[4][4] = {};
  const int tx = threadIdx.x;
  const int m0 = blockIdx.y<<6, n0 = blockIdx.x<<6;
  const int am = tx>>2, ak = (tx&3)<<2;
  const int bk = tx>>4, bn = (tx&15)<<2;
  const int mm = (tx>>4)<<2, nc = (tx&15)<<2;
  for (int kb=0; kb<K; kb+=16){
    float4 av = *reinterpret_cast<const float4*>(A + (size_t)(m0+am)*lda + kb + ak);
    As_[ak][am]=av.x; As_[ak+1][am]=av.y; As_[ak+2][am]=av.z; As_[ak+3][am]=av.w;
    *reinterpret_cast<float4*>(&Bs_[bk][bn]) =
      *reinterpret_cast<const float4*>(B + (size_t)(kb+bk)*ldb + n0 + bn);
    __syncthreads();
    #pragma unroll
    for (int k=0;k<16;k++){
      float4 a4 = *reinterpret_cast<const float4*>(&As_[k][mm]);
      float4 b4 = *reinterpret_cast<const float4*>(&Bs_[k][nc]);
      acc[0][0]=fmaf(a4.x,b4.x,acc[0][0]); acc[0][1]=fmaf(a4.x,b4.y,acc[0][1]);
      acc[0][2]=fmaf(a4.x,b4.z,acc[0][2]); acc[0][3]=fmaf(a4.x,b4.w,acc[0][3]);
      acc[1][0]=fmaf(a4.y,b4.x,acc[1][0]); acc[1][1]=fmaf(a4.y,b4.y,acc[1][1]);
      acc[1][2]=fmaf(a4.y,b4.z,acc[1][2]); acc[1][3]=fmaf(a4.y,b4.w,acc[1][3]);
      acc[2][0]=fmaf(a4.z,b4.x,acc[2][0]); acc[2][1]=fmaf(a4.z,b4.y,acc[2][1]);
      acc[2][2]=fmaf(a4.z,b4.z,acc[2][2]); acc[2][3]=fmaf(a4.z,b4.w,acc[2][3]);
      acc[3][0]=fmaf(a4.w,b4.x,acc[3][0]); acc[3][1]=fmaf(a4.w,b4.y,acc[3][1]);
      acc[3][2]=fmaf(a4.w,b4.z,acc[3][2]); acc[3][3]=fmaf(a4.w,b4.w,acc[3][3]);
    }
    __syncthreads();
  }
  #pragma unroll
  for (int r=0;r<4;r++){
    float4 v = make_float4(acc[r][0],acc[r][1],acc[r][2],acc[r][3]);
    if (relu){ v.x=fmaxf(v.x,0.f); v.y=fmaxf(v.y,0.f); v.z=fmaxf(v.z,0.f); v.w=fmaxf(v.w,0.f); }
    *reinterpret_cast<float4*>(C + (size_t)(m0+mm+r)*ldc + n0 + nc) = v;
  }
}

__global__ __launch_bounds__(256) void gemm_nt(
    float* __restrict__ C, const float* __restrict__ A, const float* __restrict__ B,
    int K, int lda, int ldb, int ldc)
{
  __shared__ float As_[16][68];
  __shared__ float Bs_[16][68];
  float acc[4][4] = {};
  const int tx = threadIdx.x;
  const int m0 = blockIdx.y<<6, n0 = blockIdx.x<<6;
  const int am = tx>>2, ak = (tx&3)<<2;
  const int mm = (tx>>4)<<2, nc = (tx&15)<<2;
  for (int kb=0; kb<K; kb+=16){
    float4 av = *reinterpret_cast<const float4*>(A + (size_t)(m0+am)*lda + kb + ak);
    As_[ak][am]=av.x; As_[ak+1][am]=av.y; As_[ak+2][am]=av.z; As_[ak+3][am]=av.w;
    float4 bv = *reinterpret_cast<const float4*>(B + (size_t)(n0+am)*ldb + kb + ak);
    Bs_[ak][am]=bv.x; Bs_[ak+1][am]=bv.y; Bs_[ak+2][am]=bv.z; Bs_[ak+3][am]=bv.w;
    __syncthreads();
    #pragma unroll
    for (int k=0;k<16;k++){
      float4 a4 = *reinterpret_cast<const float4*>(&As_[k][mm]);
      float4 b4 = *reinterpret_cast<const float4*>(&Bs_[k][nc]);
      acc[0][0]=fmaf(a4.x,b4.x,acc[0][0]); acc[0][1]=fmaf(a4.x,b4.y,acc[0][1]);
      acc[0][2]=fmaf(a4.x,b4.z,acc[0][2]); acc[0][3]=fmaf(a4.x,b4.w,acc[0][3]);
      acc[1][0]=fmaf(a4.y,b4.x,acc[1][0]); acc[1][1]=fmaf(a4.y,b4.y,acc[1][1]);
      acc[1][2]=fmaf(a4.y,b4.z,acc[1][2]); acc[1][3]=fmaf(a4.y,b4.w,acc[1][3]);
      acc[2][0]=fmaf(a4.z,b4.x,acc[2][0]); acc[2][1]=fmaf(a4.z,b4.y,acc[2][1]);
      acc[2][2]=fmaf(a4.z,b4.z,acc[2][2]); acc[2][3]=fmaf(a4.z,b4.w,acc[2][3]);
      acc[3][0]=fmaf(a4.w,b4.x,acc[3][0]); acc[3][1]=fmaf(a4.w,b4.y,acc[3][1]);
      acc[3][2]=fmaf(a4.w,b4.z,acc[3][2]); acc[3][3]=fmaf(a4.w,b4.w,acc[3][3]);
    }
    __syncthreads();
  }
  #pragma unroll
  for (int r=0;r<4;r++){
    float4 v = make_float4(acc[r][0],acc[r][1],acc[r][2],acc[r][3]);
    *reinterpret_cast<float4*>(C + (size_t)(m0+mm+r)*ldc + n0 + nc) = v;
  }
}

__global__ __launch_bounds__(256) void rowstat(const float* __restrict__ nf,
    float* __restrict__ xc, float* __restrict__ dvec)
{
  __shared__ float red[256];
  int n = blockIdx.x, tx = threadIdx.x;
  float v = nf[(size_t)n*HH + tx];
  red[tx] = v; __syncthreads();
  for (int s=128; s>0; s>>=1){ if (tx<s) red[tx]+=red[tx+s]; __syncthreads(); }
  float mean = red[0] * (1.0f/HH);
  __syncthreads();
  float d = v - mean;
  xc[(size_t)n*HH + tx] = d;
  red[tx] = d*d; __syncthreads();
  for (int s=128; s>0; s>>=1){ if (tx<s) red[tx]+=red[tx+s]; __syncthreads(); }
  if (tx==0) dvec[n] = sqrtf(red[0]);
}

__global__ __launch_bounds__(256) void rowsum(const float* __restrict__ cov,
    const float* __restrict__ dvec, float* __restrict__ dinv)
{
  __shared__ float red[256];
  int i = blockIdx.x, tx = threadIdx.x;
  float di = dvec[i];
  float s = 0.f;
  for (int jj=tx; jj<NN; jj+=256){
    float r = cov[(size_t)i*NN + jj] / (di * dvec[jj]);
    if (r != r) r = 0.f; else r = fminf(1.f, fmaxf(-1.f, r));
    s += r;
  }
  red[tx]=s; __syncthreads();
  for (int st=128; st>0; st>>=1){ if (tx<st) red[tx]+=red[tx+st]; __syncthreads(); }
  if (tx==0){
    float tot = red[0] + 1.0f;
    float p = powf(tot, -0.5f);
    if (isinf(p)) p = 0.f;
    dinv[i] = p;
  }
}

__global__ __launch_bounds__(256) void adjnorm(float* __restrict__ cov,
    const float* __restrict__ dvec, const float* __restrict__ dinv)
{
  size_t idx = (size_t)blockIdx.x*256 + threadIdx.x;
  int i = (int)(idx >> 11), jj = (int)(idx & (NN-1));
  float r = cov[idx] / (dvec[i]*dvec[jj]);
  if (r != r) r = 0.f; else r = fminf(1.f, fmaxf(-1.f, r));
  if (i==jj) r += 1.f;
  cov[idx] = dinv[i]*r*dinv[jj];
}

__global__ __launch_bounds__(128) void predk(const float* __restrict__ G2,
    const float* __restrict__ Wfc, const float* __restrict__ bfc, float* __restrict__ out)
{
  int n = blockIdx.x, tx = threadIdx.x;
  float v = G2[(size_t)n*128 + tx] * Wfc[tx];
  for (int off=32; off>0; off>>=1) v += __shfl_down(v, off);
  __shared__ float p[2];
  if ((tx&63)==0) p[tx>>6] = v;
  __syncthreads();
  if (tx==0) out[n] = p[0] + p[1] + bfc[0];
}

extern "C" void kernel_launch(void* const* d_in, const int* in_sizes, int n_in,
                              void* d_out, int out_size, void* d_ws, size_t ws_size,
                              hipStream_t stream)
{
  const float* x    = (const float*)d_in[0];
  const float* Wih0 = (const float*)d_in[1];
  const float* Whh0 = (const float*)d_in[2];
  const float* bih0 = (const float*)d_in[3];
  const float* bhh0 = (const float*)d_in[4];
  const float* Wih1 = (const float*)d_in[5];
  const float* Whh1 = (const float*)d_in[6];
  const float* bih1 = (const float*)d_in[7];
  const float* bhh1 = (const float*)d_in[8];
  const float* Wg1  = (const float*)d_in[9];
  const float* Wg2  = (const float*)d_in[10];
  const float* Wfc  = (const float*)d_in[11];
  const float* bfc  = (const float*)d_in[12];
  float* out = (float*)d_out;

  char* w = (char*)d_ws;
  auto alloc = [&](size_t bytes){ char* p = w; w += (bytes + 255) & ~(size_t)255; return p; };
  __hip_bfloat16* Xp   = (__hip_bfloat16*)alloc((size_t)NN*TT*64*2);
  __hip_bfloat16* P0hh = (__hip_bfloat16*)alloc((size_t)1024*512*2);
  __hip_bfloat16* P1ih = (__hip_bfloat16*)alloc((size_t)1024*512*2);
  __hip_bfloat16* P1hh = (__hip_bfloat16*)alloc((size_t)1024*512*2);
  __hip_bfloat16* P0ih = (__hip_bfloat16*)alloc((size_t)1024*64*2);
  __hip_bfloat16 *H0hi[2], *H0lo[2], *H1hi[2], *H1lo[2];
  for (int i=0;i<2;i++){ H0hi[i]=(__hip_bfloat16*)alloc((size_t)NN*HH*2);
                         H0lo[i]=(__hip_bfloat16*)alloc((size_t)NN*HH*2); }
  for (int i=0;i<2;i++){ H1hi[i]=(__hip_bfloat16*)alloc((size_t)NN*HH*2);
                         H1lo[i]=(__hip_bfloat16*)alloc((size_t)NN*HH*2); }
  float* c0   = (float*)alloc((size_t)NN*HH*4);
  float* c1   = (float*)alloc((size_t)NN*HH*4);
  float* nf   = (float*)alloc((size_t)NN*HH*4);
  float* xc   = (float*)alloc((size_t)NN*HH*4);
  float* cov  = (float*)alloc((size_t)NN*NN*4);
  float* t1   = (float*)alloc((size_t)NN*HH*4);
  float* G1   = (float*)alloc((size_t)NN*HH*4);
  float* t2   = (float*)alloc((size_t)NN*128*4);
  float* G2   = (float*)alloc((size_t)NN*128*4);
  float* dvec = (float*)alloc((size_t)NN*4);
  float* dinv = (float*)alloc((size_t)NN*4);

  hipLaunchKernelGGL(pack_w2, dim3(1024), dim3(256), 0, stream, Whh0, P0hh);
  hipLaunchKernelGGL(pack_w2, dim3(1024), dim3(256), 0, stream, Wih1, P1ih);
  hipLaunchKernelGGL(pack_w2, dim3(1024), dim3(256), 0, stream, Whh1, P1hh);
  hipLaunchKernelGGL(pack_w0, dim3(64),   dim3(256), 0, stream, Wih0, P0ih);
  hipLaunchKernelGGL(pack_x,  dim3(2048), dim3(256), 0, stream, x, Xp);

  // skewed recurrence: launch t runs L0(t) and L1(t-1)
  for (int t=0; t<=TT; ++t){
    const __hip_bfloat16 *h0p_hi = H0hi[(t+1)&1], *h0p_lo = H0lo[(t+1)&1];
    __hip_bfloat16 *h0o_hi = H0hi[t&1], *h0o_lo = H0lo[t&1];
    const __hip_bfloat16 *h1p_hi = H1hi[t&1], *h1p_lo = H1lo[t&1];
    __hip_bfloat16 *h1o_hi = H1hi[(t+1)&1], *h1o_lo = H1lo[(t+1)&1];
    hipLaunchKernelGGL(lstm2_step, dim3(512), dim3(256), 0, stream,
        t, Xp, P0ih, P0hh, P1ih, P1hh, bih0, bhh0, bih1, bhh1,
        h0p_hi, h0p_lo, h0o_hi, h0o_lo, h1p_hi, h1p_lo, h1o_hi, h1o_lo, c0, c1);
  }
  // final h1 (step 255, written at launch t=256) lives in H1[1]
  hipLaunchKernelGGL(recon_nf, dim3(2048), dim3(256), 0, stream, H1hi[1], H1lo[1], nf);

  hipLaunchKernelGGL(rowstat, dim3(NN), dim3(256), 0, stream, nf, xc, dvec);
  hipLaunchKernelGGL(gemm_nt, dim3(NN/64, NN/64), dim3(256), 0, stream,
      cov, xc, xc, HH, HH, HH, NN);
  hipLaunchKernelGGL(rowsum, dim3(NN), dim3(256), 0, stream, cov, dvec, dinv);
  hipLaunchKernelGGL(adjnorm, dim3(NN*NN/256), dim3(256), 0, stream, cov, dvec, dinv);

  hipLaunchKernelGGL(gemm_nn, dim3(HH/64, NN/64), dim3(256), 0, stream,
      t1, nf, Wg1, HH, HH, HH, HH, 0);
  hipLaunchKernelGGL(gemm_nn, dim3(HH/64, NN/64), dim3(256), 0, stream,
      G1, cov, t1, NN, NN, HH, HH, 1);
  hipLaunchKernelGGL(gemm_nn, dim3(128/64, NN/64), dim3(256), 0, stream,
      t2, G1, Wg2, HH, HH, 128, 128, 0);
  hipLaunchKernelGGL(gemm_nn, dim3(128/64, NN/64), dim3(256), 0, stream,
      G2, cov, t2, NN, NN, 128, 128, 0);
  hipLaunchKernelGGL(predk, dim3(NN), dim3(128), 0, stream, G2, Wfc, bfc, out);
}

// Round 11
// 5597.340 us; speedup vs baseline: 4.5582x; 1.1188x over previous
//
#include <hip/hip_runtime.h>
#include <hip/hip_bf16.h>
#include <cmath>

#define NN 2048
#define TT 256
#define DD 16
#define HH 256

typedef __attribute__((ext_vector_type(8))) short short8;
typedef __attribute__((ext_vector_type(4))) float f32x4;

__device__ __forceinline__ float sigmoidf_(float x){ return 1.0f/(1.0f+expf(-x)); }

// async 16B/lane global->LDS (LDS dest wave-uniform base; HW adds lane*16)
__device__ __forceinline__ void glds16(const __hip_bfloat16* g, __hip_bfloat16* l){
  __builtin_amdgcn_global_load_lds(
      (const __attribute__((address_space(1))) void*)g,
      (__attribute__((address_space(3))) void*)l, 16, 0, 0);
}

// ---------------- packing ----------------
// W (1024x256) -> P (1024x512): [hi | lo]
__global__ __launch_bounds__(256) void pack_w2(const float* __restrict__ W,
                                               __hip_bfloat16* __restrict__ P){
  int tid = blockIdx.x*256 + threadIdx.x;   // 1024 blocks
  int r = tid >> 8, k = tid & 255;
  float w = W[tid];
  __hip_bfloat16 h = __float2bfloat16(w);
  __hip_bfloat16 l = __float2bfloat16(w - __bfloat162float(h));
  size_t base = (size_t)r*512;
  P[base + k] = h; P[base + 256 + k] = l;
}
// Wih0 (1024 x 16) -> (1024 x 64): [hi | hi | lo | 0] (pairs with x [hi|lo|hi|0])
__global__ __launch_bounds__(256) void pack_w0(const float* __restrict__ W,
                                               __hip_bfloat16* __restrict__ P){
  int tid = blockIdx.x*256 + threadIdx.x;   // 64 blocks
  int r = tid >> 4, k = tid & 15;
  float w = W[tid];
  __hip_bfloat16 h = __float2bfloat16(w);
  __hip_bfloat16 l = __float2bfloat16(w - __bfloat162float(h));
  size_t base = (size_t)r*64;
  P[base + k] = h; P[base + 16 + k] = h; P[base + 32 + k] = l;
  P[base + 48 + k] = __float2bfloat16(0.0f);
}
// x (N,T,16) -> Xp (N,T,64): [hi | lo | hi | 0]
__global__ __launch_bounds__(256) void pack_x(const float* __restrict__ x,
                                              __hip_bfloat16* __restrict__ Xp){
  int tid = blockIdx.x*256 + threadIdx.x;   // 2048 blocks
  const float* xr = x + (size_t)tid*16;
  __hip_bfloat16* o = Xp + (size_t)tid*64;
  for (int k=0;k<16;k++){
    float v = xr[k];
    __hip_bfloat16 h = __float2bfloat16(v);
    __hip_bfloat16 l = __float2bfloat16(v - __bfloat162float(h));
    o[k] = h; o[16+k] = l; o[32+k] = h; o[48+k] = __float2bfloat16(0.0f);
  }
}
__global__ __launch_bounds__(256) void recon_nf(const __hip_bfloat16* __restrict__ hi,
    const __hip_bfloat16* __restrict__ lo, float* __restrict__ nf){
  int tid = blockIdx.x*256 + threadIdx.x;
  nf[tid] = __bfloat162float(hi[tid]) + __bfloat162float(lo[tid]);
}

// ---------------- GEMM segments: BK=128 (two 64-panels per barrier) ----------------
// Block tile: 128 m x 16 j x 4 gates. 4 waves; wave stages its 32 m-rows of A and
// gate-group wv's 16 rows of B. Per BK=128 chunk: stage panel0->buf0 AND
// panel1->buf1, one sync (drains both), MFMA both panels, sync. All loads drain
// at the immediately-following barrier (proven R8 pattern; 2x work per drain).
__device__ __forceinline__ void mm_dual(
    const __hip_bfloat16* __restrict__ A, size_t lda,
    const __hip_bfloat16* __restrict__ Bhi, const __hip_bfloat16* __restrict__ Blo,
    size_t ldb, int Klen,
    int m0, int j0, int wv, int lane, int rr, int sw8, int frow,
    f32x4 (&acc)[2][4],
    __hip_bfloat16* As0, __hip_bfloat16* As1,
    __hip_bfloat16* Bh0, __hip_bfloat16* Bh1,
    __hip_bfloat16* Bl0, __hip_bfloat16* Bl1)
{
  const size_t arow = (size_t)(m0 + wv*32 + rr)*lda + sw8;
  const size_t brow = (size_t)(wv*256 + j0 + rr)*ldb + sw8;
  for (int kb=0; kb<Klen; kb+=128){
    // stage panel 0 (k = kb) -> buf0
    {
      const __hip_bfloat16* Ab = A + arow + kb;
      __hip_bfloat16* Ad = As0 + (wv*32)*64;
      #pragma unroll
      for (int c2=0;c2<4;c2++) glds16(Ab + (size_t)(c2*8)*lda, Ad + c2*8*64);
      const __hip_bfloat16* Bb1 = Bhi + brow + kb;
      __hip_bfloat16* Bd1 = Bh0 + (wv<<4)*64;
      glds16(Bb1, Bd1); glds16(Bb1 + (size_t)8*ldb, Bd1 + 8*64);
      const __hip_bfloat16* Bb2 = Blo + brow + kb;
      __hip_bfloat16* Bd2 = Bl0 + (wv<<4)*64;
      glds16(Bb2, Bd2); glds16(Bb2 + (size_t)8*ldb, Bd2 + 8*64);
    }
    // stage panel 1 (k = kb+64) -> buf1
    {
      const __hip_bfloat16* Ab = A + arow + kb + 64;
      __hip_bfloat16* Ad = As1 + (wv*32)*64;
      #pragma unroll
      for (int c2=0;c2<4;c2++) glds16(Ab + (size_t)(c2*8)*lda, Ad + c2*8*64);
      const __hip_bfloat16* Bb1 = Bhi + brow + kb + 64;
      __hip_bfloat16* Bd1 = Bh1 + (wv<<4)*64;
      glds16(Bb1, Bd1); glds16(Bb1 + (size_t)8*ldb, Bd1 + 8*64);
      const __hip_bfloat16* Bb2 = Blo + brow + kb + 64;
      __hip_bfloat16* Bd2 = Bl1 + (wv<<4)*64;
      glds16(Bb2, Bd2); glds16(Bb2 + (size_t)8*ldb, Bd2 + 8*64);
    }
    __syncthreads();          // drains both panels' loads
    #pragma unroll
    for (int pn=0; pn<2; ++pn){
      const __hip_bfloat16* Asr = pn ? As1 : As0;
      const __hip_bfloat16* Bhr = pn ? Bh1 : Bh0;
      const __hip_bfloat16* Blr = pn ? Bl1 : Bl0;
      #pragma unroll
      for (int w2=0; w2<2; ++w2){
        const int sl8 = ((((w2<<2) + (lane>>4)) ^ (lane&7)) << 3);
        short8 a0 = *(const short8*)&Asr[(wv*32 +      frow)*64 + sl8];
        short8 a1 = *(const short8*)&Asr[(wv*32 + 16 + frow)*64 + sl8];
        #pragma unroll
        for (int g=0; g<4; ++g){
          short8 b1 = *(const short8*)&Bhr[((g<<4) + frow)*64 + sl8];
          acc[0][g] = __builtin_amdgcn_mfma_f32_16x16x32_bf16(a0, b1, acc[0][g], 0,0,0);
          acc[1][g] = __builtin_amdgcn_mfma_f32_16x16x32_bf16(a1, b1, acc[1][g], 0,0,0);
          short8 b2 = *(const short8*)&Blr[((g<<4) + frow)*64 + sl8];
          acc[0][g] = __builtin_amdgcn_mfma_f32_16x16x32_bf16(a0, b2, acc[0][g], 0,0,0);
          acc[1][g] = __builtin_amdgcn_mfma_f32_16x16x32_bf16(a1, b2, acc[1][g], 0,0,0);
        }
      }
    }
    __syncthreads();
  }
}

// single-B, BK=128 (two panels per barrier); Klen multiple of 128
__device__ __forceinline__ void mm_single2(
    const __hip_bfloat16* __restrict__ A, size_t lda,
    const __hip_bfloat16* __restrict__ B, size_t ldb, int Klen,
    int m0, int j0, int wv, int lane, int rr, int sw8, int frow,
    f32x4 (&acc)[2][4],
    __hip_bfloat16* As0, __hip_bfloat16* As1,
    __hip_bfloat16* Bh0, __hip_bfloat16* Bh1)
{
  const size_t arow = (size_t)(m0 + wv*32 + rr)*lda + sw8;
  const size_t brow = (size_t)(wv*256 + j0 + rr)*ldb + sw8;
  for (int kb=0; kb<Klen; kb+=128){
    {
      const __hip_bfloat16* Ab = A + arow + kb;
      __hip_bfloat16* Ad = As0 + (wv*32)*64;
      #pragma unroll
      for (int c2=0;c2<4;c2++) glds16(Ab + (size_t)(c2*8)*lda, Ad + c2*8*64);
      const __hip_bfloat16* Bb1 = B + brow + kb;
      __hip_bfloat16* Bd1 = Bh0 + (wv<<4)*64;
      glds16(Bb1, Bd1); glds16(Bb1 + (size_t)8*ldb, Bd1 + 8*64);
    }
    {
      const __hip_bfloat16* Ab = A + arow + kb + 64;
      __hip_bfloat16* Ad = As1 + (wv*32)*64;
      #pragma unroll
      for (int c2=0;c2<4;c2++) glds16(Ab + (size_t)(c2*8)*lda, Ad + c2*8*64);
      const __hip_bfloat16* Bb1 = B + brow + kb + 64;
      __hip_bfloat16* Bd1 = Bh1 + (wv<<4)*64;
      glds16(Bb1, Bd1); glds16(Bb1 + (size_t)8*ldb, Bd1 + 8*64);
    }
    __syncthreads();
    #pragma unroll
    for (int pn=0; pn<2; ++pn){
      const __hip_bfloat16* Asr = pn ? As1 : As0;
      const __hip_bfloat16* Bhr = pn ? Bh1 : Bh0;
      #pragma unroll
      for (int w2=0; w2<2; ++w2){
        const int sl8 = ((((w2<<2) + (lane>>4)) ^ (lane&7)) << 3);
        short8 a0 = *(const short8*)&Asr[(wv*32 +      frow)*64 + sl8];
        short8 a1 = *(const short8*)&Asr[(wv*32 + 16 + frow)*64 + sl8];
        #pragma unroll
        for (int g=0; g<4; ++g){
          short8 b1 = *(const short8*)&Bhr[((g<<4) + frow)*64 + sl8];
          acc[0][g] = __builtin_amdgcn_mfma_f32_16x16x32_bf16(a0, b1, acc[0][g], 0,0,0);
          acc[1][g] = __builtin_amdgcn_mfma_f32_16x16x32_bf16(a1, b1, acc[1][g], 0,0,0);
        }
      }
    }
    __syncthreads();
  }
}

// single-B, one 64-panel (for the K=64 x-chunk) — exact R8 shape
__device__ __forceinline__ void mm_single64(
    const __hip_bfloat16* __restrict__ A, size_t lda,
    const __hip_bfloat16* __restrict__ B, size_t ldb,
    int m0, int j0, int wv, int lane, int rr, int sw8, int frow,
    f32x4 (&acc)[2][4],
    __hip_bfloat16* As0, __hip_bfloat16* Bh0)
{
  {
    const __hip_bfloat16* Ab = A + (size_t)(m0 + wv*32 + rr)*lda + sw8;
    __hip_bfloat16* Ad = As0 + (wv*32)*64;
    #pragma unroll
    for (int c2=0;c2<4;c2++) glds16(Ab + (size_t)(c2*8)*lda, Ad + c2*8*64);
    const __hip_bfloat16* Bb1 = B + (size_t)(wv*256 + j0 + rr)*ldb + sw8;
    __hip_bfloat16* Bd1 = Bh0 + (wv<<4)*64;
    glds16(Bb1, Bd1); glds16(Bb1 + (size_t)8*ldb, Bd1 + 8*64);
  }
  __syncthreads();
  #pragma unroll
  for (int w2=0; w2<2; ++w2){
    const int sl8 = ((((w2<<2) + (lane>>4)) ^ (lane&7)) << 3);
    short8 a0 = *(const short8*)&As0[(wv*32 +      frow)*64 + sl8];
    short8 a1 = *(const short8*)&As0[(wv*32 + 16 + frow)*64 + sl8];
    #pragma unroll
    for (int g=0; g<4; ++g){
      short8 b1 = *(const short8*)&Bh0[((g<<4) + frow)*64 + sl8];
      acc[0][g] = __builtin_amdgcn_mfma_f32_16x16x32_bf16(a0, b1, acc[0][g], 0,0,0);
      acc[1][g] = __builtin_amdgcn_mfma_f32_16x16x32_bf16(a1, b1, acc[1][g], 0,0,0);
    }
  }
  __syncthreads();
}

// ---------------- fused two-layer skewed LSTM step (MFMA bf16x3) ----------------
// Launch t: blocks [0,256) layer0 step t; [256,512) layer1 step t-1.
__global__ __launch_bounds__(256, 2) void lstm2_step(
    int t,
    const __hip_bfloat16* __restrict__ Xp,
    const __hip_bfloat16* __restrict__ P0ih,
    const __hip_bfloat16* __restrict__ P0hh,
    const __hip_bfloat16* __restrict__ P1ih,
    const __hip_bfloat16* __restrict__ P1hh,
    const float* __restrict__ bih0, const float* __restrict__ bhh0,
    const float* __restrict__ bih1, const float* __restrict__ bhh1,
    const __hip_bfloat16* __restrict__ h0p_hi, const __hip_bfloat16* __restrict__ h0p_lo,
    __hip_bfloat16* __restrict__ h0o_hi, __hip_bfloat16* __restrict__ h0o_lo,
    const __hip_bfloat16* __restrict__ h1p_hi, const __hip_bfloat16* __restrict__ h1p_lo,
    __hip_bfloat16* __restrict__ h1o_hi, __hip_bfloat16* __restrict__ h1o_lo,
    float* __restrict__ c0, float* __restrict__ c1)
{
  __shared__ __align__(16) __hip_bfloat16 As0[128*64], As1[128*64];   // 2 x 16 KB
  __shared__ __align__(16) __hip_bfloat16 Bh0[64*64],  Bh1[64*64];    // 2 x 8 KB
  __shared__ __align__(16) __hip_bfloat16 Bl0[64*64],  Bl1[64*64];    // 2 x 8 KB

  const int bid = blockIdx.x;
  const bool isL0 = bid < 256;
  if (isL0 && t >= TT) return;
  if (!isL0 && t == 0) return;
  const int idx = bid & 255;
  const int m0 = (idx >> 4) << 7;
  const int j0 = (idx & 15) << 4;
  const int lane = threadIdx.x & 63, wv = threadIdx.x >> 6;
  const int rr = lane >> 3;
  const int sw8 = (((lane & 7) ^ rr) << 3);     // source-side XOR swizzle
  const int frow = lane & 15;

  f32x4 acc[2][4] = {};                 // [m-subtile][gate]

  if (isL0){
    if (t != 0){
      mm_dual   (h0p_hi, 256, P0hh, P0hh+256, 512, 256,
                 m0, j0, wv, lane, rr, sw8, frow, acc, As0, As1, Bh0, Bh1, Bl0, Bl1);
      mm_single2(h0p_lo, 256, P0hh, 512, 256,
                 m0, j0, wv, lane, rr, sw8, frow, acc, As0, As1, Bh0, Bh1);
    }
    mm_single64(Xp + (size_t)t*64, (size_t)TT*64, P0ih, 64,
                m0, j0, wv, lane, rr, sw8, frow, acc, As0, Bh0);
  } else {
    mm_dual   (h0p_hi, 256, P1ih, P1ih+256, 512, 256,
               m0, j0, wv, lane, rr, sw8, frow, acc, As0, As1, Bh0, Bh1, Bl0, Bl1);
    mm_single2(h0p_lo, 256, P1ih, 512, 256,
               m0, j0, wv, lane, rr, sw8, frow, acc, As0, As1, Bh0, Bh1);
    if (t != 1){
      mm_dual   (h1p_hi, 256, P1hh, P1hh+256, 512, 256,
                 m0, j0, wv, lane, rr, sw8, frow, acc, As0, As1, Bh0, Bh1, Bl0, Bl1);
      mm_single2(h1p_lo, 256, P1hh, 512, 256,
                 m0, j0, wv, lane, rr, sw8, frow, acc, As0, As1, Bh0, Bh1);
    }
  }

  // epilogue: lane holds all 4 gates. C map: col=lane&15, row=(lane>>4)*4+r
  const int j = j0 + frow;
  const float* bih = isL0 ? bih0 : bih1;
  const float* bhh = isL0 ? bhh0 : bhh1;
  float* cst = isL0 ? c0 : c1;
  __hip_bfloat16* ohi = isL0 ? h0o_hi : h1o_hi;
  __hip_bfloat16* olo = isL0 ? h0o_lo : h1o_lo;
  const int first = isL0 ? (t==0) : (t==1);
  const float b0 = bih[j]        + bhh[j];
  const float b1 = bih[HH + j]   + bhh[HH + j];
  const float b2 = bih[2*HH + j] + bhh[2*HH + j];
  const float b3 = bih[3*HH + j] + bhh[3*HH + j];
  #pragma unroll
  for (int mt=0; mt<2; ++mt){
    const int mrb = m0 + wv*32 + mt*16 + ((lane>>4)<<2);
    #pragma unroll
    for (int r=0; r<4; ++r){
      const size_t mi = (size_t)(mrb + r)*HH + j;
      float gi = acc[mt][0][r] + b0;
      float gf = acc[mt][1][r] + b1;
      float gg = acc[mt][2][r] + b2;
      float go = acc[mt][3][r] + b3;
      float cold = first ? 0.f : cst[mi];
      float cn = sigmoidf_(gf)*cold + sigmoidf_(gi)*tanhf(gg);
      float hv = sigmoidf_(go)*tanhf(cn);
      cst[mi] = cn;
      __hip_bfloat16 hb = __float2bfloat16(hv);
      ohi[mi] = hb;
      olo[mi] = __float2bfloat16(hv - __bfloat162float(hb));
    }
  }
}

// ---------------- fp32 tail (unchanged, proven) ----------------
__global__ __launch_bounds__(256) void gemm_nn(
    float* __restrict__ C, const float* __restrict__ A, const float* __restrict__ B,
    int K, int lda, int ldb, int ldc, int relu)
{
  __shared__ float As_[16][68];
  __shared__ float Bs_[16][64];
  float acc[4][4] = {};
  const int tx = threadIdx.x;
  const int m0 = blockIdx.y<<6, n0 = blockIdx.x<<6;
  const int am = tx>>2, ak = (tx&3)<<2;
  const int bk = tx>>4, bn = (tx&15)<<2;
  const int mm = (tx>>4)<<2, nc = (tx&15)<<2;
  for (int kb=0; kb<K; kb+=16){
    float4 av = *reinterpret_cast<const float4*>(A + (size_t)(m0+am)*lda + kb + ak);
    As_[ak][am]=av.x; As_[ak+1][am]=av.y; As_[ak+2][am]=av.z; As_[ak+3][am]=av.w;
    *reinterpret_cast<float4*>(&Bs_[bk][bn]) =
      *reinterpret_cast<const float4*>(B + (size_t)(kb+bk)*ldb + n0 + bn);
    __syncthreads();
    #pragma unroll
    for (int k=0;k<16;k++){
      float4 a4 = *reinterpret_cast<const float4*>(&As_[k][mm]);
      float4 b4 = *reinterpret_cast<const float4*>(&Bs_[k][nc]);
      acc[0][0]=fmaf(a4.x,b4.x,acc[0][0]); acc[0][1]=fmaf(a4.x,b4.y,acc[0][1]);
      acc[0][2]=fmaf(a4.x,b4.z,acc[0][2]); acc[0][3]=fmaf(a4.x,b4.w,acc[0][3]);
      acc[1][0]=fmaf(a4.y,b4.x,acc[1][0]); acc[1][1]=fmaf(a4.y,b4.y,acc[1][1]);
      acc[1][2]=fmaf(a4.y,b4.z,acc[1][2]); acc[1][3]=fmaf(a4.y,b4.w,acc[1][3]);
      acc[2][0]=fmaf(a4.z,b4.x,acc[2][0]); acc[2][1]=fmaf(a4.z,b4.y,acc[2][1]);
      acc[2][2]=fmaf(a4.z,b4.z,acc[2][2]); acc[2][3]=fmaf(a4.z,b4.w,acc[2][3]);
      acc[3][0]=fmaf(a4.w,b4.x,acc[3][0]); acc[3][1]=fmaf(a4.w,b4.y,acc[3][1]);
      acc[3][2]=fmaf(a4.w,b4.z,acc[3][2]); acc[3][3]=fmaf(a4.w,b4.w,acc[3][3]);
    }
    __syncthreads();
  }
  #pragma unroll
  for (int r=0;r<4;r++){
    float4 v = make_float4(acc[r][0],acc[r][1],acc[r][2],acc[r][3]);
    if (relu){ v.x=fmaxf(v.x,0.f); v.y=fmaxf(v.y,0.f); v.z=fmaxf(v.z,0.f); v.w=fmaxf(v.w,0.f); }
    *reinterpret_cast<float4*>(C + (size_t)(m0+mm+r)*ldc + n0 + nc) = v;
  }
}

__global__ __launch_bounds__(256) void gemm_nt(
    float* __restrict__ C, const float* __restrict__ A, const float* __restrict__ B,
    int K, int lda, int ldb, int ldc)
{
  __shared__ float As_[16][68];
  __shared__ float Bs_[16][68];
  float acc[4][4] = {};
  const int tx = threadIdx.x;
  const int m0 = blockIdx.y<<6, n0 = blockIdx.x<<6;
  const int am = tx>>2, ak = (tx&3)<<2;
  const int mm = (tx>>4)<<2, nc = (tx&15)<<2;
  for (int kb=0; kb<K; kb+=16){
    float4 av = *reinterpret_cast<const float4*>(A + (size_t)(m0+am)*lda + kb + ak);
    As_[ak][am]=av.x; As_[ak+1][am]=av.y; As_[ak+2][am]=av.z; As_[ak+3][am]=av.w;
    float4 bv = *reinterpret_cast<const float4*>(B + (size_t)(n0+am)*ldb + kb + ak);
    Bs_[ak][am]=bv.x; Bs_[ak+1][am]=bv.y; Bs_[ak+2][am]=bv.z; Bs_[ak+3][am]=bv.w;
    __syncthreads();
    #pragma unroll
    for (int k=0;k<16;k++){
      float4 a4 = *reinterpret_cast<const float4*>(&As_[k][mm]);
      float4 b4 = *reinterpret_cast<const float4*>(&Bs_[k][nc]);
      acc[0][0]=fmaf(a4.x,b4.x,acc[0][0]); acc[0][1]=fmaf(a4.x,b4.y,acc[0][1]);
      acc[0][2]=fmaf(a4.x,b4.z,acc[0][2]); acc[0][3]=fmaf(a4.x,b4.w,acc[0][3]);
      acc[1][0]=fmaf(a4.y,b4.x,acc[1][0]); acc[1][1]=fmaf(a4.y,b4.y,acc[1][1]);
      acc[1][2]=fmaf(a4.y,b4.z,acc[1][2]); acc[1][3]=fmaf(a4.y,b4.w,acc[1][3]);
      acc[2][0]=fmaf(a4.z,b4.x,acc[2][0]); acc[2][1]=fmaf(a4.z,b4.y,acc[2][1]);
      acc[2][2]=fmaf(a4.z,b4.z,acc[2][2]); acc[2][3]=fmaf(a4.z,b4.w,acc[2][3]);
      acc[3][0]=fmaf(a4.w,b4.x,acc[3][0]); acc[3][1]=fmaf(a4.w,b4.y,acc[3][1]);
      acc[3][2]=fmaf(a4.w,b4.z,acc[3][2]); acc[3][3]=fmaf(a4.w,b4.w,acc[3][3]);
    }
    __syncthreads();
  }
  #pragma unroll
  for (int r=0;r<4;r++){
    float4 v = make_float4(acc[r][0],acc[r][1],acc[r][2],acc[r][3]);
    *reinterpret_cast<float4*>(C + (size_t)(m0+mm+r)*ldc + n0 + nc) = v;
  }
}

__global__ __launch_bounds__(256) void rowstat(const float* __restrict__ nf,
    float* __restrict__ xc, float* __restrict__ dvec)
{
  __shared__ float red[256];
  int n = blockIdx.x, tx = threadIdx.x;
  float v = nf[(size_t)n*HH + tx];
  red[tx] = v; __syncthreads();
  for (int s=128; s>0; s>>=1){ if (tx<s) red[tx]+=red[tx+s]; __syncthreads(); }
  float mean = red[0] * (1.0f/HH);
  __syncthreads();
  float d = v - mean;
  xc[(size_t)n*HH + tx] = d;
  red[tx] = d*d; __syncthreads();
  for (int s=128; s>0; s>>=1){ if (tx<s) red[tx]+=red[tx+s]; __syncthreads(); }
  if (tx==0) dvec[n] = sqrtf(red[0]);
}

__global__ __launch_bounds__(256) void rowsum(const float* __restrict__ cov,
    const float* __restrict__ dvec, float* __restrict__ dinv)
{
  __shared__ float red[256];
  int i = blockIdx.x, tx = threadIdx.x;
  float di = dvec[i];
  float s = 0.f;
  for (int jj=tx; jj<NN; jj+=256){
    float r = cov[(size_t)i*NN + jj] / (di * dvec[jj]);
    if (r != r) r = 0.f; else r = fminf(1.f, fmaxf(-1.f, r));
    s += r;
  }
  red[tx]=s; __syncthreads();
  for (int st=128; st>0; st>>=1){ if (tx<st) red[tx]+=red[tx+st]; __syncthreads(); }
  if (tx==0){
    float tot = red[0] + 1.0f;
    float p = powf(tot, -0.5f);
    if (isinf(p)) p = 0.f;
    dinv[i] = p;
  }
}

__global__ __launch_bounds__(256) void adjnorm(float* __restrict__ cov,
    const float* __restrict__ dvec, const float* __restrict__ dinv)
{
  size_t idx = (size_t)blockIdx.x*256 + threadIdx.x;
  int i = (int)(idx >> 11), jj = (int)(idx & (NN-1));
  float r = cov[idx] / (dvec[i]*dvec[jj]);
  if (r != r) r = 0.f; else r = fminf(1.f, fmaxf(-1.f, r));
  if (i==jj) r += 1.f;
  cov[idx] = dinv[i]*r*dinv[jj];
}

__global__ __launch_bounds__(128) void predk(const float* __restrict__ G2,
    const float* __restrict__ Wfc, const float* __restrict__ bfc, float* __restrict__ out)
{
  int n = blockIdx.x, tx = threadIdx.x;
  float v = G2[(size_t)n*128 + tx] * Wfc[tx];
  for (int off=32; off>0; off>>=1) v += __shfl_down(v, off);
  __shared__ float p[2];
  if ((tx&63)==0) p[tx>>6] = v;
  __syncthreads();
  if (tx==0) out[n] = p[0] + p[1] + bfc[0];
}

extern "C" void kernel_launch(void* const* d_in, const int* in_sizes, int n_in,
                              void* d_out, int out_size, void* d_ws, size_t ws_size,
                              hipStream_t stream)
{
  const float* x    = (const float*)d_in[0];
  const float* Wih0 = (const float*)d_in[1];
  const float* Whh0 = (const float*)d_in[2];
  const float* bih0 = (const float*)d_in[3];
  const float* bhh0 = (const float*)d_in[4];
  const float* Wih1 = (const float*)d_in[5];
  const float* Whh1 = (const float*)d_in[6];
  const float* bih1 = (const float*)d_in[7];
  const float* bhh1 = (const float*)d_in[8];
  const float* Wg1  = (const float*)d_in[9];
  const float* Wg2  = (const float*)d_in[10];
  const float* Wfc  = (const float*)d_in[11];
  const float* bfc  = (const float*)d_in[12];
  float* out = (float*)d_out;

  char* w = (char*)d_ws;
  auto alloc = [&](size_t bytes){ char* p = w; w += (bytes + 255) & ~(size_t)255; return p; };
  __hip_bfloat16* Xp   = (__hip_bfloat16*)alloc((size_t)NN*TT*64*2);
  __hip_bfloat16* P0hh = (__hip_bfloat16*)alloc((size_t)1024*512*2);
  __hip_bfloat16* P1ih = (__hip_bfloat16*)alloc((size_t)1024*512*2);
  __hip_bfloat16* P1hh = (__hip_bfloat16*)alloc((size_t)1024*512*2);
  __hip_bfloat16* P0ih = (__hip_bfloat16*)alloc((size_t)1024*64*2);
  __hip_bfloat16 *H0hi[2], *H0lo[2], *H1hi[2], *H1lo[2];
  for (int i=0;i<2;i++){ H0hi[i]=(__hip_bfloat16*)alloc((size_t)NN*HH*2);
                         H0lo[i]=(__hip_bfloat16*)alloc((size_t)NN*HH*2); }
  for (int i=0;i<2;i++){ H1hi[i]=(__hip_bfloat16*)alloc((size_t)NN*HH*2);
                         H1lo[i]=(__hip_bfloat16*)alloc((size_t)NN*HH*2); }
  float* c0   = (float*)alloc((size_t)NN*HH*4);
  float* c1   = (float*)alloc((size_t)NN*HH*4);
  float* nf   = (float*)alloc((size_t)NN*HH*4);
  float* xc   = (float*)alloc((size_t)NN*HH*4);
  float* cov  = (float*)alloc((size_t)NN*NN*4);
  float* t1   = (float*)alloc((size_t)NN*HH*4);
  float* G1   = (float*)alloc((size_t)NN*HH*4);
  float* t2   = (float*)alloc((size_t)NN*128*4);
  float* G2   = (float*)alloc((size_t)NN*128*4);
  float* dvec = (float*)alloc((size_t)NN*4);
  float* dinv = (float*)alloc((size_t)NN*4);

  hipLaunchKernelGGL(pack_w2, dim3(1024), dim3(256), 0, stream, Whh0, P0hh);
  hipLaunchKernelGGL(pack_w2, dim3(1024), dim3(256), 0, stream, Wih1, P1ih);
  hipLaunchKernelGGL(pack_w2, dim3(1024), dim3(256), 0, stream, Whh1, P1hh);
  hipLaunchKernelGGL(pack_w0, dim3(64),   dim3(256), 0, stream, Wih0, P0ih);
  hipLaunchKernelGGL(pack_x,  dim3(2048), dim3(256), 0, stream, x, Xp);

  // skewed recurrence: launch t runs L0(t) and L1(t-1)
  for (int t=0; t<=TT; ++t){
    const __hip_bfloat16 *h0p_hi = H0hi[(t+1)&1], *h0p_lo = H0lo[(t+1)&1];
    __hip_bfloat16 *h0o_hi = H0hi[t&1], *h0o_lo = H0lo[t&1];
    const __hip_bfloat16 *h1p_hi = H1hi[t&1], *h1p_lo = H1lo[t&1];
    __hip_bfloat16 *h1o_hi = H1hi[(t+1)&1], *h1o_lo = H1lo[(t+1)&1];
    hipLaunchKernelGGL(lstm2_step, dim3(512), dim3(256), 0, stream,
        t, Xp, P0ih, P0hh, P1ih, P1hh, bih0, bhh0, bih1, bhh1,
        h0p_hi, h0p_lo, h0o_hi, h0o_lo, h1p_hi, h1p_lo, h1o_hi, h1o_lo, c0, c1);
  }
  // final h1 (step 255, written at launch t=256) lives in H1[1]
  hipLaunchKernelGGL(recon_nf, dim3(2048), dim3(256), 0, stream, H1hi[1], H1lo[1], nf);

  hipLaunchKernelGGL(rowstat, dim3(NN), dim3(256), 0, stream, nf, xc, dvec);
  hipLaunchKernelGGL(gemm_nt, dim3(NN/64, NN/64), dim3(256), 0, stream,
      cov, xc, xc, HH, HH, HH, NN);
  hipLaunchKernelGGL(rowsum, dim3(NN), dim3(256), 0, stream, cov, dvec, dinv);
  hipLaunchKernelGGL(adjnorm, dim3(NN*NN/256), dim3(256), 0, stream, cov, dvec, dinv);

  hipLaunchKernelGGL(gemm_nn, dim3(HH/64, NN/64), dim3(256), 0, stream,
      t1, nf, Wg1, HH, HH, HH, HH, 0);
  hipLaunchKernelGGL(gemm_nn, dim3(HH/64, NN/64), dim3(256), 0, stream,
      G1, cov, t1, NN, NN, HH, HH, 1);
  hipLaunchKernelGGL(gemm_nn, dim3(128/64, NN/64), dim3(256), 0, stream,
      t2, G1, Wg2, HH, HH, 128, 128, 0);
  hipLaunchKernelGGL(gemm_nn, dim3(128/64, NN/64), dim3(256), 0, stream,
      G2, cov, t2, NN, NN, 128, 128, 0);
  hipLaunchKernelGGL(predk, dim3(NN), dim3(128), 0, stream, G2, Wfc, bfc, out);
}